// Round 4
// baseline (2034.952 us; speedup 1.0000x reference)
//
#include <hip/hip_runtime.h>

#define N_NODES 100000
#define N_EDGES 1600000
#define CH 64
#define NLAYERS 3
#define NBUCK 391          // ceil(100000/256) buckets of 256 dst nodes
#define EPB 1024           // edges per partition block (1563 blocks -> real parallelism)
#define STASH 20

static __device__ __forceinline__ float4 ld4(const float* p){ return *(const float4*)p; }

// ---- A0: bucket histogram (bucket = dst>>8) ----
__global__ __launch_bounds__(256) void bhist_kernel(const int* __restrict__ dst, int* __restrict__ bcnt){
  __shared__ int h[NBUCK];
  int tid = threadIdx.x;
  for (int i = tid; i < NBUCK; i += 256) h[i] = 0;
  __syncthreads();
  int base = blockIdx.x * EPB;
  #pragma unroll
  for (int k = 0; k < EPB/256; ++k) {
    int e = base + k*256 + tid;
    if (e < N_EDGES) atomicAdd(&h[dst[e] >> 8], 1);
  }
  __syncthreads();
  for (int i = tid; i < NBUCK; i += 256) if (h[i]) atomicAdd(&bcnt[i], h[i]);
}

// ---- A1: scan buckets -> bstart[0..NBUCK], btail working copy ----
__global__ __launch_bounds__(512) void bscan_kernel(const int* __restrict__ bcnt,
                                                    int* __restrict__ bstart, int* __restrict__ btail){
  __shared__ int s[512];
  int t = threadIdx.x;
  int v = (t < NBUCK) ? bcnt[t] : 0;
  s[t] = v; __syncthreads();
  #pragma unroll
  for (int o = 1; o < 512; o <<= 1){
    int u = (t >= o) ? s[t-o] : 0;
    __syncthreads();
    s[t] += u;
    __syncthreads();
  }
  if (t <= NBUCK) {
    int ex = (t == 0) ? 0 : s[t-1];
    bstart[t] = ex;
    if (t < NBUCK) btail[t] = ex;
  }
}

// ---- A2: partition edges into bucket-contiguous (src,dst) pairs ----
__global__ __launch_bounds__(256) void part_kernel(const int* __restrict__ src, const int* __restrict__ dst,
                                                   int* __restrict__ btail, int2* __restrict__ pairs){
  __shared__ int lpos[NBUCK];
  __shared__ int gb[NBUCK];
  int tid = threadIdx.x;
  for (int i = tid; i < NBUCK; i += 256) lpos[i] = 0;
  __syncthreads();
  int base = blockIdx.x * EPB;
  int es[EPB/256], ed[EPB/256], er[EPB/256];
  #pragma unroll
  for (int k = 0; k < EPB/256; ++k) {
    int e = base + k*256 + tid;
    if (e < N_EDGES) {
      es[k] = src[e];
      ed[k] = dst[e];
      er[k] = atomicAdd(&lpos[ed[k] >> 8], 1);
    }
  }
  __syncthreads();
  for (int i = tid; i < NBUCK; i += 256) {
    int c = lpos[i];
    gb[i] = c ? atomicAdd(&btail[i], c) : 0;
  }
  __syncthreads();
  #pragma unroll
  for (int k = 0; k < EPB/256; ++k) {
    int e = base + k*256 + tid;
    if (e < N_EDGES) pairs[gb[ed[k] >> 8] + er[k]] = make_int2(es[k], ed[k]);
  }
}

// ---- B: per-bucket CSR build. srclist entry = src | (local256 << 20)  (src < 2^17) ----
__global__ __launch_bounds__(256) void csr_kernel(const int2* __restrict__ pairs, const int* __restrict__ bstart,
                                                  int* __restrict__ off, int* __restrict__ srclist){
  __shared__ int c[256];
  __shared__ int s[256];
  __shared__ int cur[256];
  int t = threadIdx.x;
  int b = blockIdx.x;
  int e0 = bstart[b], e1 = bstart[b+1];
  c[t] = 0;
  __syncthreads();
  int2 st[STASH];
  int k = 0;
  for (int i = e0 + t; i < e1; i += 256, ++k) {
    int2 pr = pairs[i];
    if (k < STASH) st[k] = pr;
    atomicAdd(&c[pr.y & 255], 1);
  }
  __syncthreads();
  int v = c[t];
  s[t] = v; __syncthreads();
  #pragma unroll
  for (int o = 1; o < 256; o <<= 1){
    int u = (t >= o) ? s[t-o] : 0;
    __syncthreads();
    s[t] += u;
    __syncthreads();
  }
  int excl = s[t] - v;
  cur[t] = excl;
  int n = (b << 8) + t;
  if (n <= N_NODES) off[n] = e0 + excl;
  __syncthreads();
  k = 0;
  for (int i = e0 + t; i < e1; i += 256, ++k) {
    int2 pr = (k < STASH) ? st[k] : pairs[i];
    int p = atomicAdd(&cur[pr.y & 255], 1);
    srclist[e0 + p] = pr.x | ((pr.y & 255) << 20);
  }
}

// ---- fold BN into weights/biases ----
__global__ __launch_bounds__(256) void prep_kernel(
    const float* __restrict__ W1, const float* __restrict__ b1,
    const float* __restrict__ g1, const float* __restrict__ be1,
    const float* __restrict__ W2, const float* __restrict__ b2,
    const float* __restrict__ g2, const float* __restrict__ be2,
    const float* __restrict__ bng, const float* __restrict__ bnb,
    float* __restrict__ Wf, float* __restrict__ bf, float* __restrict__ ogb){
  const float s = 0.9999950000374997f;   // 1/sqrt(1+1e-5)
  int i = blockIdx.x*256 + threadIdx.x;
  if (i < NLAYERS*4096) {
    int l = i >> 12, rem = i & 4095, j = rem & 63;
    Wf[l*8192 + rem]        = W1[i] * g1[l*64+j] * s;
    Wf[l*8192 + 4096 + rem] = W2[i] * g2[l*64+j] * s;
  }
  if (i < NLAYERS*64) {
    int l = i >> 6, j = i & 63;
    bf[l*128 + j]      = b1[i]*g1[i]*s + be1[i];
    bf[l*128 + 64 + j] = b2[i]*g2[i]*s + be2[i];
    ogb[i]                 = bng[i]*s;
    ogb[NLAYERS*64 + i]    = bnb[i];
  }
}

// ---- fused layer: edge-parallel LDS-atomic gather -> GEMM1 -> GEMM2 -> BN epilogue ----
// LDS 33KB -> 4 blocks/CU. Rows per thread = lq+16r (stride 68 words == 4 mod 32: 2-way, free).
__global__ __launch_bounds__(256) void layer_kernel(const float* __restrict__ x, const int* __restrict__ off,
                                                    const int* __restrict__ srclist, const float* __restrict__ eps,
                                                    const float* __restrict__ Wf, const float* __restrict__ bf,
                                                    const float* __restrict__ ogb, int layer,
                                                    float* __restrict__ out, int relu_out){
  __shared__ __align__(16) float Ws[64*64];     // W1, later W2
  __shared__ __align__(16) float Hs[64*68];     // +4 pad
  int tid = threadIdx.x;
  int b = blockIdx.x;
  const float* Wg = Wf + layer*8192;
  #pragma unroll
  for (int it = 0; it < 4; ++it) {
    int i = (tid + it*256) * 4;
    *(float4*)&Ws[i] = ld4(Wg + i);
  }
  int lq = tid & 15, jg = tid >> 4;
  int j0 = jg << 2;
  float ep = 1.0f + eps[layer];
  // self-term init: rows lq+16r, cols j0
  #pragma unroll
  for (int r = 0; r < 4; ++r) {
    int nl = lq + 16*r;
    int n = b*64 + nl;
    float4 v = make_float4(0.f,0.f,0.f,0.f);
    if (n < N_NODES) {
      float4 xv = ld4(x + (size_t)n*CH + j0);
      v = make_float4(ep*xv.x, ep*xv.y, ep*xv.z, ep*xv.w);
    }
    *(float4*)&Hs[nl*68 + j0] = v;
  }
  __syncthreads();
  // edge-parallel gather: 16 edges in flight, 16 lanes x float4 per edge
  {
    int c = lq << 2;
    int nbase = b*64;
    int nend = nbase + 64; if (nend > N_NODES) nend = N_NODES;
    int e_begin = off[nbase];
    int e_end = off[nend];
    int dbase = (b & 3) << 6;
    for (int e = e_begin + jg; e < e_end; e += 16) {
      int sp = srclist[e];
      int sidx = sp & 0xFFFFF;
      int nl = ((unsigned)sp >> 20) - dbase;
      float4 v = ld4(x + (size_t)sidx*CH + c);
      float* h = &Hs[nl*68 + c];
      atomicAdd(h+0, v.x);
      atomicAdd(h+1, v.y);
      atomicAdd(h+2, v.z);
      atomicAdd(h+3, v.w);
    }
  }
  __syncthreads();

  const float4 bias1 = ld4(bf + layer*128 + j0);
  const float4 bias2 = ld4(bf + layer*128 + 64 + j0);
  const float4 og4   = ld4(ogb + layer*64 + j0);
  const float4 ob4   = ld4(ogb + NLAYERS*64 + layer*64 + j0);

  float acc[4][4];
  #pragma unroll
  for (int r = 0; r < 4; ++r){ acc[r][0]=bias1.x; acc[r][1]=bias1.y; acc[r][2]=bias1.z; acc[r][3]=bias1.w; }

  for (int k = 0; k < 64; k += 4) {
    float4 a[4], bb[4];
    #pragma unroll
    for (int r = 0; r < 4; ++r) a[r] = *(const float4*)&Hs[(lq + 16*r)*68 + k];
    #pragma unroll
    for (int kk = 0; kk < 4; ++kk) bb[kk] = *(const float4*)&Ws[(k+kk)*64 + j0];
    #pragma unroll
    for (int r = 0; r < 4; ++r){
      const float* ar = (const float*)&a[r];
      #pragma unroll
      for (int kk = 0; kk < 4; ++kk){
        float av = ar[kk];
        acc[r][0] = fmaf(av, bb[kk].x, acc[r][0]);
        acc[r][1] = fmaf(av, bb[kk].y, acc[r][1]);
        acc[r][2] = fmaf(av, bb[kk].z, acc[r][2]);
        acc[r][3] = fmaf(av, bb[kk].w, acc[r][3]);
      }
    }
  }
  __syncthreads();   // all GEMM1 reads of Hs & Ws done
  #pragma unroll
  for (int r = 0; r < 4; ++r){
    float4 hv = make_float4(fmaxf(acc[r][0],0.f), fmaxf(acc[r][1],0.f),
                            fmaxf(acc[r][2],0.f), fmaxf(acc[r][3],0.f));
    *(float4*)&Hs[(lq + 16*r)*68 + j0] = hv;
  }
  #pragma unroll
  for (int it = 0; it < 4; ++it) {
    int i = (tid + it*256) * 4;
    *(float4*)&Ws[i] = ld4(Wg + 4096 + i);    // W2 into the same buffer
  }
  __syncthreads();

  #pragma unroll
  for (int r = 0; r < 4; ++r){ acc[r][0]=bias2.x; acc[r][1]=bias2.y; acc[r][2]=bias2.z; acc[r][3]=bias2.w; }
  for (int k = 0; k < 64; k += 4) {
    float4 a[4], bb[4];
    #pragma unroll
    for (int r = 0; r < 4; ++r) a[r] = *(const float4*)&Hs[(lq + 16*r)*68 + k];
    #pragma unroll
    for (int kk = 0; kk < 4; ++kk) bb[kk] = *(const float4*)&Ws[(k+kk)*64 + j0];
    #pragma unroll
    for (int r = 0; r < 4; ++r){
      const float* ar = (const float*)&a[r];
      #pragma unroll
      for (int kk = 0; kk < 4; ++kk){
        float av = ar[kk];
        acc[r][0] = fmaf(av, bb[kk].x, acc[r][0]);
        acc[r][1] = fmaf(av, bb[kk].y, acc[r][1]);
        acc[r][2] = fmaf(av, bb[kk].z, acc[r][2]);
        acc[r][3] = fmaf(av, bb[kk].w, acc[r][3]);
      }
    }
  }

  #pragma unroll
  for (int r = 0; r < 4; ++r){
    int gnode = b*64 + lq + 16*r;
    if (gnode < N_NODES) {
      float o0 = fmaf(og4.x, fmaxf(acc[r][0],0.f), ob4.x);
      float o1 = fmaf(og4.y, fmaxf(acc[r][1],0.f), ob4.y);
      float o2 = fmaf(og4.z, fmaxf(acc[r][2],0.f), ob4.z);
      float o3 = fmaf(og4.w, fmaxf(acc[r][3],0.f), ob4.w);
      if (relu_out){ o0=fmaxf(o0,0.f); o1=fmaxf(o1,0.f); o2=fmaxf(o2,0.f); o3=fmaxf(o3,0.f); }
      *(float4*)(out + (size_t)gnode*CH + j0) = make_float4(o0,o1,o2,o3);
    }
  }
}

extern "C" void kernel_launch(void* const* d_in, const int* in_sizes, int n_in,
                              void* d_out, int out_size, void* d_ws, size_t ws_size,
                              hipStream_t stream) {
  const float* x0  = (const float*)d_in[0];
  const int*   ei  = (const int*)d_in[1];
  const float* eps = (const float*)d_in[2];
  const float* W1  = (const float*)d_in[3];
  const float* b1  = (const float*)d_in[4];
  const float* g1  = (const float*)d_in[5];
  const float* be1 = (const float*)d_in[6];
  const float* W2  = (const float*)d_in[7];
  const float* b2  = (const float*)d_in[8];
  const float* g2  = (const float*)d_in[9];
  const float* be2 = (const float*)d_in[10];
  const float* bng = (const float*)d_in[11];
  const float* bnb = (const float*)d_in[12];
  const int* src = ei;
  const int* dst = ei + N_EDGES;
  float* OUT = (float*)d_out;

  char* p = (char*)d_ws;
  auto carve = [&](size_t bytes)->char*{ char* r = p; p += (bytes + 255) & ~(size_t)255; return r; };
  int*   off     = (int*)carve((N_NODES+1)*sizeof(int));
  int*   bcnt    = (int*)carve(NBUCK*sizeof(int));
  int*   bstart  = (int*)carve((NBUCK+1)*sizeof(int));
  int*   btail   = (int*)carve(NBUCK*sizeof(int));
  // pairs (12.8 MB) is dead after csr_kernel; T (25.6 MB) aliases the same region.
  char*  big     = carve((size_t)N_NODES*CH*sizeof(float));   // 25.6 MB
  int2*  pairs   = (int2*)big;
  float* T       = (float*)big;
  int*   srclist = (int*)carve((size_t)N_EDGES*sizeof(int));
  float* Wf      = (float*)carve((size_t)NLAYERS*2*4096*sizeof(float));
  float* bfb     = (float*)carve((size_t)NLAYERS*2*64*sizeof(float));
  float* ogb     = (float*)carve((size_t)2*NLAYERS*64*sizeof(float));

  const int npart = (N_EDGES + EPB - 1)/EPB;   // 1563
  hipMemsetAsync(bcnt, 0, NBUCK*sizeof(int), stream);
  bhist_kernel<<<npart, 256, 0, stream>>>(dst, bcnt);
  bscan_kernel<<<1, 512, 0, stream>>>(bcnt, bstart, btail);
  part_kernel<<<npart, 256, 0, stream>>>(src, dst, btail, pairs);
  csr_kernel<<<NBUCK, 256, 0, stream>>>(pairs, bstart, off, srclist);
  prep_kernel<<<48, 256, 0, stream>>>(W1,b1,g1,be1,W2,b2,g2,be2,bng,bnb,Wf,bfb,ogb);

  const int nlb = (N_NODES + 63)/64;
  // Ping-pong: l0: x0 -> OUT, l1: OUT -> T, l2: T -> OUT (final result in d_out).
  layer_kernel<<<nlb, 256, 0, stream>>>(x0,  off, srclist, eps, Wf, bfb, ogb, 0, OUT, 1);
  layer_kernel<<<nlb, 256, 0, stream>>>(OUT, off, srclist, eps, Wf, bfb, ogb, 1, T,   1);
  layer_kernel<<<nlb, 256, 0, stream>>>(T,   off, srclist, eps, Wf, bfb, ogb, 2, OUT, 0);
}

// Round 5
// 392.548 us; speedup vs baseline: 5.1840x; 5.1840x over previous
//
#include <hip/hip_runtime.h>

#define N_NODES 100000
#define N_EDGES 1600000
#define CH 64
#define NLAYERS 3
#define NBUCK 391          // ceil(100000/256) buckets of 256 dst nodes
#define EPB 2048           // edges per partition block (782 blocks)
#define STASH 20

static __device__ __forceinline__ float4 ld4(const float* p){ return *(const float4*)p; }
static __device__ __forceinline__ float bf2f(unsigned short u){ return __uint_as_float(((unsigned)u)<<16); }
static __device__ __forceinline__ unsigned short f2bf(float f){
  unsigned u = __float_as_uint(f);
  return (unsigned short)((u + 0x7fffu + ((u>>16)&1u)) >> 16);   // RTN-even
}

// ---- A0: bucket histogram (bucket = dst>>8) ----
__global__ __launch_bounds__(256) void bhist_kernel(const int* __restrict__ dst, int* __restrict__ bcnt){
  __shared__ int h[NBUCK];
  int tid = threadIdx.x;
  for (int i = tid; i < NBUCK; i += 256) h[i] = 0;
  __syncthreads();
  int base = blockIdx.x * EPB;
  #pragma unroll
  for (int k = 0; k < EPB/256; ++k) {
    int e = base + k*256 + tid;
    if (e < N_EDGES) atomicAdd(&h[dst[e] >> 8], 1);
  }
  __syncthreads();
  for (int i = tid; i < NBUCK; i += 256) if (h[i]) atomicAdd(&bcnt[i], h[i]);
}

// ---- A1: scan buckets -> bstart[0..NBUCK], btail working copy ----
__global__ __launch_bounds__(512) void bscan_kernel(const int* __restrict__ bcnt,
                                                    int* __restrict__ bstart, int* __restrict__ btail){
  __shared__ int s[512];
  int t = threadIdx.x;
  int v = (t < NBUCK) ? bcnt[t] : 0;
  s[t] = v; __syncthreads();
  #pragma unroll
  for (int o = 1; o < 512; o <<= 1){
    int u = (t >= o) ? s[t-o] : 0;
    __syncthreads();
    s[t] += u;
    __syncthreads();
  }
  if (t <= NBUCK) {
    int ex = (t == 0) ? 0 : s[t-1];
    bstart[t] = ex;
    if (t < NBUCK) btail[t] = ex;
  }
}

// ---- A2: partition edges into bucket-contiguous (src,dst) pairs ----
__global__ __launch_bounds__(256) void part_kernel(const int* __restrict__ src, const int* __restrict__ dst,
                                                   int* __restrict__ btail, int2* __restrict__ pairs){
  __shared__ int lpos[NBUCK];
  __shared__ int gb[NBUCK];
  int tid = threadIdx.x;
  for (int i = tid; i < NBUCK; i += 256) lpos[i] = 0;
  __syncthreads();
  int base = blockIdx.x * EPB;
  int es[EPB/256], ed[EPB/256], er[EPB/256];
  #pragma unroll
  for (int k = 0; k < EPB/256; ++k) {
    int e = base + k*256 + tid;
    if (e < N_EDGES) {
      es[k] = src[e];
      ed[k] = dst[e];
      er[k] = atomicAdd(&lpos[ed[k] >> 8], 1);
    }
  }
  __syncthreads();
  for (int i = tid; i < NBUCK; i += 256) {
    int c = lpos[i];
    gb[i] = c ? atomicAdd(&btail[i], c) : 0;
  }
  __syncthreads();
  #pragma unroll
  for (int k = 0; k < EPB/256; ++k) {
    int e = base + k*256 + tid;
    if (e < N_EDGES) pairs[gb[ed[k] >> 8] + er[k]] = make_int2(es[k], ed[k]);
  }
}

// ---- B: per-bucket CSR build (off + srclist) ----
__global__ __launch_bounds__(256) void csr_kernel(const int2* __restrict__ pairs, const int* __restrict__ bstart,
                                                  int* __restrict__ off, int* __restrict__ srclist){
  __shared__ int c[256];
  __shared__ int s[256];
  __shared__ int cur[256];
  int t = threadIdx.x;
  int b = blockIdx.x;
  int e0 = bstart[b], e1 = bstart[b+1];
  c[t] = 0;
  __syncthreads();
  int2 st[STASH];
  int k = 0;
  for (int i = e0 + t; i < e1; i += 256, ++k) {
    int2 pr = pairs[i];
    if (k < STASH) st[k] = pr;
    atomicAdd(&c[pr.y & 255], 1);
  }
  __syncthreads();
  int v = c[t];
  s[t] = v; __syncthreads();
  #pragma unroll
  for (int o = 1; o < 256; o <<= 1){
    int u = (t >= o) ? s[t-o] : 0;
    __syncthreads();
    s[t] += u;
    __syncthreads();
  }
  int excl = s[t] - v;
  cur[t] = excl;
  int n = (b << 8) + t;
  if (n <= N_NODES) off[n] = e0 + excl;
  __syncthreads();
  k = 0;
  for (int i = e0 + t; i < e1; i += 256, ++k) {
    int2 pr = (k < STASH) ? st[k] : pairs[i];
    int p = atomicAdd(&cur[pr.y & 255], 1);
    srclist[e0 + p] = pr.x;
  }
}

// ---- fold BN into weights/biases ----
__global__ __launch_bounds__(256) void prep_kernel(
    const float* __restrict__ W1, const float* __restrict__ b1,
    const float* __restrict__ g1, const float* __restrict__ be1,
    const float* __restrict__ W2, const float* __restrict__ b2,
    const float* __restrict__ g2, const float* __restrict__ be2,
    const float* __restrict__ bng, const float* __restrict__ bnb,
    float* __restrict__ Wf, float* __restrict__ bf, float* __restrict__ ogb){
  const float s = 0.9999950000374997f;   // 1/sqrt(1+1e-5)
  int i = blockIdx.x*256 + threadIdx.x;
  if (i < NLAYERS*4096) {
    int l = i >> 12, rem = i & 4095, j = rem & 63;
    Wf[l*8192 + rem]        = W1[i] * g1[l*64+j] * s;
    Wf[l*8192 + 4096 + rem] = W2[i] * g2[l*64+j] * s;
  }
  if (i < NLAYERS*64) {
    int l = i >> 6, j = i & 63;
    bf[l*128 + j]      = b1[i]*g1[i]*s + be1[i];
    bf[l*128 + 64 + j] = b2[i]*g2[i]*s + be2[i];
    ogb[i]                 = bng[i]*s;
    ogb[NLAYERS*64 + i]    = bnb[i];
  }
}

// ---- x0 (fp32) -> XB (bf16) ----
__global__ __launch_bounds__(256) void xcvt_kernel(const float* __restrict__ x, unsigned short* __restrict__ xb){
  int i = (blockIdx.x*256 + threadIdx.x)*4;
  if (i < N_NODES*CH) {
    float4 v = ld4(x + i);
    ushort4 w = make_ushort4(f2bf(v.x), f2bf(v.y), f2bf(v.z), f2bf(v.w));
    *(ushort4*)(xb + i) = w;
  }
}

// ---- aggregation: T[n] = (1+eps)*xb[n] + sum_{e: dst=n} xb[src[e]]  (bf16 in, fp32 out) ----
// 16 lanes per node, lane owns 4 channels. Dual accumulators (2 loads in flight / thread).
__global__ __launch_bounds__(256) void agg_kernel(const unsigned short* __restrict__ xb,
                                                  const int* __restrict__ off, const int* __restrict__ srclist,
                                                  const float* __restrict__ eps, int layer,
                                                  float* __restrict__ T){
  int g = blockIdx.x*256 + threadIdx.x;
  int n = g >> 4;
  if (n >= N_NODES) return;
  int c = (g & 15) << 2;
  const unsigned short* xr = xb + c;
  int e0 = off[n], e1 = off[n+1];
  float a0=0.f,a1=0.f,a2=0.f,a3=0.f, b0=0.f,b1=0.f,b2=0.f,b3=0.f;
  int e = e0;
  for (; e+2 <= e1; e += 2) {
    int s0 = srclist[e], s1 = srclist[e+1];
    ushort4 u0 = *(const ushort4*)(xr + (size_t)s0*CH);
    ushort4 u1 = *(const ushort4*)(xr + (size_t)s1*CH);
    a0 += bf2f(u0.x); a1 += bf2f(u0.y); a2 += bf2f(u0.z); a3 += bf2f(u0.w);
    b0 += bf2f(u1.x); b1 += bf2f(u1.y); b2 += bf2f(u1.z); b3 += bf2f(u1.w);
  }
  if (e < e1) {
    int s0 = srclist[e];
    ushort4 u0 = *(const ushort4*)(xr + (size_t)s0*CH);
    a0 += bf2f(u0.x); a1 += bf2f(u0.y); a2 += bf2f(u0.z); a3 += bf2f(u0.w);
  }
  float ep = 1.0f + eps[layer];
  ushort4 sv = *(const ushort4*)(xr + (size_t)n*CH);
  a0 = fmaf(ep, bf2f(sv.x), a0 + b0);
  a1 = fmaf(ep, bf2f(sv.y), a1 + b1);
  a2 = fmaf(ep, bf2f(sv.z), a2 + b2);
  a3 = fmaf(ep, bf2f(sv.w), a3 + b3);
  *(float4*)(T + (size_t)n*CH + c) = make_float4(a0,a1,a2,a3);
}

// ---- MLP: T -> (GEMM1+BN+ReLU) -> (GEMM2+BN+ReLU) -> outer BN; out bf16 (mode 1) or fp32 (mode 0) ----
// 64 nodes/block. Rows per thread = lq+16r (LDS stride 68: 2-way max, free). Ws reloaded with W2.
__global__ __launch_bounds__(256) void mlp_kernel(const float* __restrict__ T, const float* __restrict__ Wf,
                                                  const float* __restrict__ bf, const float* __restrict__ ogb,
                                                  int layer, float* __restrict__ outf,
                                                  unsigned short* __restrict__ outb, int relu_out){
  __shared__ __align__(16) float Ws[64*64];     // W1, later W2
  __shared__ __align__(16) float Hs[64*68];     // +4 pad
  int tid = threadIdx.x;
  int b = blockIdx.x;
  const float* Wg = Wf + layer*8192;
  #pragma unroll
  for (int it = 0; it < 4; ++it) {
    int i = (tid + it*256) * 4;
    *(float4*)&Ws[i] = ld4(Wg + i);
  }
  long gbase = (long)b * 4096;
  #pragma unroll
  for (int it = 0; it < 4; ++it) {
    int idx = (tid + it*256) * 4;
    int nrow = idx >> 6, kk = idx & 63;
    float4 v = make_float4(0.f,0.f,0.f,0.f);
    if (gbase + idx < (long)N_NODES*CH) v = ld4(T + gbase + idx);
    *(float4*)&Hs[nrow*68 + kk] = v;
  }
  __syncthreads();

  int lq = tid & 15, jg = tid >> 4;
  int j0 = jg << 2;
  const float4 bias1 = ld4(bf + layer*128 + j0);
  const float4 bias2 = ld4(bf + layer*128 + 64 + j0);
  const float4 og4   = ld4(ogb + layer*64 + j0);
  const float4 ob4   = ld4(ogb + NLAYERS*64 + layer*64 + j0);

  float acc[4][4];
  #pragma unroll
  for (int r = 0; r < 4; ++r){ acc[r][0]=bias1.x; acc[r][1]=bias1.y; acc[r][2]=bias1.z; acc[r][3]=bias1.w; }

  for (int k = 0; k < 64; k += 4) {
    float4 a[4], bb[4];
    #pragma unroll
    for (int r = 0; r < 4; ++r) a[r] = *(const float4*)&Hs[(lq + 16*r)*68 + k];
    #pragma unroll
    for (int kk = 0; kk < 4; ++kk) bb[kk] = *(const float4*)&Ws[(k+kk)*64 + j0];
    #pragma unroll
    for (int r = 0; r < 4; ++r){
      const float* ar = (const float*)&a[r];
      #pragma unroll
      for (int kk = 0; kk < 4; ++kk){
        float av = ar[kk];
        acc[r][0] = fmaf(av, bb[kk].x, acc[r][0]);
        acc[r][1] = fmaf(av, bb[kk].y, acc[r][1]);
        acc[r][2] = fmaf(av, bb[kk].z, acc[r][2]);
        acc[r][3] = fmaf(av, bb[kk].w, acc[r][3]);
      }
    }
  }
  __syncthreads();   // GEMM1 reads of Hs & Ws done
  #pragma unroll
  for (int r = 0; r < 4; ++r){
    float4 hv = make_float4(fmaxf(acc[r][0],0.f), fmaxf(acc[r][1],0.f),
                            fmaxf(acc[r][2],0.f), fmaxf(acc[r][3],0.f));
    *(float4*)&Hs[(lq + 16*r)*68 + j0] = hv;
  }
  #pragma unroll
  for (int it = 0; it < 4; ++it) {
    int i = (tid + it*256) * 4;
    *(float4*)&Ws[i] = ld4(Wg + 4096 + i);    // W2 into the same buffer
  }
  __syncthreads();

  #pragma unroll
  for (int r = 0; r < 4; ++r){ acc[r][0]=bias2.x; acc[r][1]=bias2.y; acc[r][2]=bias2.z; acc[r][3]=bias2.w; }
  for (int k = 0; k < 64; k += 4) {
    float4 a[4], bb[4];
    #pragma unroll
    for (int r = 0; r < 4; ++r) a[r] = *(const float4*)&Hs[(lq + 16*r)*68 + k];
    #pragma unroll
    for (int kk = 0; kk < 4; ++kk) bb[kk] = *(const float4*)&Ws[(k+kk)*64 + j0];
    #pragma unroll
    for (int r = 0; r < 4; ++r){
      const float* ar = (const float*)&a[r];
      #pragma unroll
      for (int kk = 0; kk < 4; ++kk){
        float av = ar[kk];
        acc[r][0] = fmaf(av, bb[kk].x, acc[r][0]);
        acc[r][1] = fmaf(av, bb[kk].y, acc[r][1]);
        acc[r][2] = fmaf(av, bb[kk].z, acc[r][2]);
        acc[r][3] = fmaf(av, bb[kk].w, acc[r][3]);
      }
    }
  }

  #pragma unroll
  for (int r = 0; r < 4; ++r){
    int gnode = b*64 + lq + 16*r;
    if (gnode < N_NODES) {
      float o0 = fmaf(og4.x, fmaxf(acc[r][0],0.f), ob4.x);
      float o1 = fmaf(og4.y, fmaxf(acc[r][1],0.f), ob4.y);
      float o2 = fmaf(og4.z, fmaxf(acc[r][2],0.f), ob4.z);
      float o3 = fmaf(og4.w, fmaxf(acc[r][3],0.f), ob4.w);
      if (relu_out) {
        ushort4 w = make_ushort4(f2bf(fmaxf(o0,0.f)), f2bf(fmaxf(o1,0.f)),
                                 f2bf(fmaxf(o2,0.f)), f2bf(fmaxf(o3,0.f)));
        *(ushort4*)(outb + (size_t)gnode*CH + j0) = w;
      } else {
        *(float4*)(outf + (size_t)gnode*CH + j0) = make_float4(o0,o1,o2,o3);
      }
    }
  }
}

extern "C" void kernel_launch(void* const* d_in, const int* in_sizes, int n_in,
                              void* d_out, int out_size, void* d_ws, size_t ws_size,
                              hipStream_t stream) {
  const float* x0  = (const float*)d_in[0];
  const int*   ei  = (const int*)d_in[1];
  const float* eps = (const float*)d_in[2];
  const float* W1  = (const float*)d_in[3];
  const float* b1  = (const float*)d_in[4];
  const float* g1  = (const float*)d_in[5];
  const float* be1 = (const float*)d_in[6];
  const float* W2  = (const float*)d_in[7];
  const float* b2  = (const float*)d_in[8];
  const float* g2  = (const float*)d_in[9];
  const float* be2 = (const float*)d_in[10];
  const float* bng = (const float*)d_in[11];
  const float* bnb = (const float*)d_in[12];
  const int* src = ei;
  const int* dst = ei + N_EDGES;
  float* OUT = (float*)d_out;

  char* p = (char*)d_ws;
  auto carve = [&](size_t bytes)->char*{ char* r = p; p += (bytes + 255) & ~(size_t)255; return r; };
  int*   off     = (int*)carve((N_NODES+1)*sizeof(int));
  int*   bcnt    = (int*)carve(NBUCK*sizeof(int));
  int*   bstart  = (int*)carve((NBUCK+1)*sizeof(int));
  int*   btail   = (int*)carve(NBUCK*sizeof(int));
  // pairs (12.8 MB) dead after csr_kernel; T (25.6 MB fp32) aliases the same region.
  char*  big     = carve((size_t)N_NODES*CH*sizeof(float));   // 25.6 MB
  int2*  pairs   = (int2*)big;
  float* T       = (float*)big;
  unsigned short* XB = (unsigned short*)carve((size_t)N_NODES*CH*sizeof(unsigned short)); // 12.8 MB
  int*   srclist = (int*)carve((size_t)N_EDGES*sizeof(int));
  float* Wf      = (float*)carve((size_t)NLAYERS*2*4096*sizeof(float));
  float* bfb     = (float*)carve((size_t)NLAYERS*2*64*sizeof(float));
  float* ogb     = (float*)carve((size_t)2*NLAYERS*64*sizeof(float));

  const int npart = (N_EDGES + EPB - 1)/EPB;   // 782
  hipMemsetAsync(bcnt, 0, NBUCK*sizeof(int), stream);
  bhist_kernel<<<npart, 256, 0, stream>>>(dst, bcnt);
  bscan_kernel<<<1, 512, 0, stream>>>(bcnt, bstart, btail);
  part_kernel<<<npart, 256, 0, stream>>>(src, dst, btail, pairs);
  csr_kernel<<<NBUCK, 256, 0, stream>>>(pairs, bstart, off, srclist);
  prep_kernel<<<48, 256, 0, stream>>>(W1,b1,g1,be1,W2,b2,g2,be2,bng,bnb,Wf,bfb,ogb);
  xcvt_kernel<<<(N_NODES*CH/4 + 255)/256, 256, 0, stream>>>(x0, XB);

  const int nab = (N_NODES*16 + 255)/256;   // 6250
  const int nmb = (N_NODES + 63)/64;        // 1563
  // Split kernels: stream ordering makes XB reuse safe (agg fully reads XB before mlp rewrites it).
  for (int l = 0; l < NLAYERS; ++l) {
    agg_kernel<<<nab, 256, 0, stream>>>(XB, off, srclist, eps, l, T);
    mlp_kernel<<<nmb, 256, 0, stream>>>(T, Wf, bfb, ogb, l, OUT, XB, (l < NLAYERS-1) ? 1 : 0);
  }
}

// Round 6
// 350.628 us; speedup vs baseline: 5.8037x; 1.1196x over previous
//
#include <hip/hip_runtime.h>

#define N_NODES 100000
#define N_EDGES 1600000
#define CH 64
#define NLAYERS 3
#define NBUCK 391          // ceil(100000/256) buckets of 256 dst nodes
#define SLAB 5120          // slab capacity per bucket (mean 4092, sd 64 -> +16 sigma)
#define EPB 2048           // edges per partition block (782 blocks)
#define STASH 12

static __device__ __forceinline__ float4 ld4(const float* p){ return *(const float4*)p; }
static __device__ __forceinline__ float bf2f(unsigned short u){ return __uint_as_float(((unsigned)u)<<16); }
static __device__ __forceinline__ unsigned short f2bf(float f){
  unsigned u = __float_as_uint(f);
  return (unsigned short)((u + 0x7fffu + ((u>>16)&1u)) >> 16);   // RTN-even
}

// ---- btail init: slab base cursors ----
__global__ __launch_bounds__(256) void binit_kernel(int* __restrict__ btail){
  int i = blockIdx.x*256 + threadIdx.x;
  if (i < NBUCK) btail[i] = i*SLAB;
}

// ---- partition edges into per-bucket slabs of (src,dst) pairs ----
__global__ __launch_bounds__(256) void part_kernel(const int* __restrict__ src, const int* __restrict__ dst,
                                                   int* __restrict__ btail, int2* __restrict__ pairs){
  __shared__ int lpos[NBUCK];
  __shared__ int gb[NBUCK];
  int tid = threadIdx.x;
  for (int i = tid; i < NBUCK; i += 256) lpos[i] = 0;
  __syncthreads();
  int base = blockIdx.x * EPB;
  int es[EPB/256], ed[EPB/256], er[EPB/256];
  #pragma unroll
  for (int k = 0; k < EPB/256; ++k) {
    int e = base + k*256 + tid;
    if (e < N_EDGES) {
      es[k] = src[e];
      ed[k] = dst[e];
      er[k] = atomicAdd(&lpos[ed[k] >> 8], 1);
    }
  }
  __syncthreads();
  for (int i = tid; i < NBUCK; i += 256) {
    int c = lpos[i];
    gb[i] = c ? atomicAdd(&btail[i], c) : 0;
  }
  __syncthreads();
  #pragma unroll
  for (int k = 0; k < EPB/256; ++k) {
    int e = base + k*256 + tid;
    if (e < N_EDGES) {
      int bk = ed[k] >> 8;
      int idx = gb[bk] + er[k];
      if (idx < (bk+1)*SLAB)                    // memory-safety clamp (statistically never)
        pairs[idx] = make_int2(es[k], ed[k]);
    }
  }
}

// ---- per-bucket CSR build: off_start/off_end + srclist (slab layout) ----
__global__ __launch_bounds__(512) void csr_kernel(const int2* __restrict__ pairs, const int* __restrict__ btail,
                                                  int* __restrict__ offs, int* __restrict__ offe,
                                                  int* __restrict__ srclist){
  __shared__ int c[256];
  __shared__ int s[256];
  __shared__ int cur[256];
  int t = threadIdx.x;
  int b = blockIdx.x;
  int e0 = b*SLAB;
  int e1 = btail[b]; int emax = e0 + SLAB; if (e1 > emax) e1 = emax;
  if (t < 256) c[t] = 0;
  __syncthreads();
  int2 st[STASH];
  int k = 0;
  for (int i = e0 + t; i < e1; i += 512, ++k) {
    int2 pr = pairs[i];
    if (k < STASH) st[k] = pr;
    atomicAdd(&c[pr.y & 255], 1);
  }
  __syncthreads();
  int v = (t < 256) ? c[t] : 0;
  if (t < 256) s[t] = v;
  __syncthreads();
  #pragma unroll
  for (int o = 1; o < 256; o <<= 1){
    int u = 0;
    if (t < 256 && t >= o) u = s[t-o];
    __syncthreads();
    if (t < 256) s[t] += u;
    __syncthreads();
  }
  if (t < 256) {
    int excl = s[t] - v;
    cur[t] = excl;
    int n = (b << 8) + t;
    if (n < N_NODES) { offs[n] = e0 + excl; offe[n] = e0 + excl + v; }
  }
  __syncthreads();
  k = 0;
  for (int i = e0 + t; i < e1; i += 512, ++k) {
    int2 pr = (k < STASH) ? st[k] : pairs[i];
    int p = atomicAdd(&cur[pr.y & 255], 1);
    srclist[e0 + p] = pr.x;
  }
}

// ---- fold BN into weights/biases ----
__global__ __launch_bounds__(256) void prep_kernel(
    const float* __restrict__ W1, const float* __restrict__ b1,
    const float* __restrict__ g1, const float* __restrict__ be1,
    const float* __restrict__ W2, const float* __restrict__ b2,
    const float* __restrict__ g2, const float* __restrict__ be2,
    const float* __restrict__ bng, const float* __restrict__ bnb,
    float* __restrict__ Wf, float* __restrict__ bf, float* __restrict__ ogb){
  const float s = 0.9999950000374997f;   // 1/sqrt(1+1e-5)
  int i = blockIdx.x*256 + threadIdx.x;
  if (i < NLAYERS*4096) {
    int l = i >> 12, rem = i & 4095, j = rem & 63;
    Wf[l*8192 + rem]        = W1[i] * g1[l*64+j] * s;
    Wf[l*8192 + 4096 + rem] = W2[i] * g2[l*64+j] * s;
  }
  if (i < NLAYERS*64) {
    int l = i >> 6, j = i & 63;
    bf[l*128 + j]      = b1[i]*g1[i]*s + be1[i];
    bf[l*128 + 64 + j] = b2[i]*g2[i]*s + be2[i];
    ogb[i]                 = bng[i]*s;
    ogb[NLAYERS*64 + i]    = bnb[i];
  }
}

// ---- x0 (fp32) -> XB (bf16) ----
__global__ __launch_bounds__(256) void xcvt_kernel(const float* __restrict__ x, unsigned short* __restrict__ xb){
  int i = (blockIdx.x*256 + threadIdx.x)*4;
  if (i < N_NODES*CH) {
    float4 v = ld4(x + i);
    ushort4 w = make_ushort4(f2bf(v.x), f2bf(v.y), f2bf(v.z), f2bf(v.w));
    *(ushort4*)(xb + i) = w;
  }
}

// ---- aggregation v2: 8 lanes/node, 8 ch/lane (uint4=8xbf16 loads), 4 independent chains ----
__global__ __launch_bounds__(256) void agg_kernel(const unsigned short* __restrict__ xb,
                                                  const int* __restrict__ offs, const int* __restrict__ offe,
                                                  const int* __restrict__ srclist,
                                                  const float* __restrict__ eps, int layer,
                                                  float* __restrict__ T){
  int g = blockIdx.x*256 + threadIdx.x;
  int n = g >> 3;
  if (n >= N_NODES) return;
  int c = (g & 7) << 3;             // 8 channels per lane
  const unsigned short* xr = xb + c;
  int e0 = offs[n], e1 = offe[n];
  float A[8] = {0,0,0,0,0,0,0,0};
  float B[8] = {0,0,0,0,0,0,0,0};
  float C[8] = {0,0,0,0,0,0,0,0};
  float D[8] = {0,0,0,0,0,0,0,0};
  #define ADD8(acc, u) { \
    acc[0] += __uint_as_float((u).x << 16); acc[1] += __uint_as_float((u).x & 0xffff0000u); \
    acc[2] += __uint_as_float((u).y << 16); acc[3] += __uint_as_float((u).y & 0xffff0000u); \
    acc[4] += __uint_as_float((u).z << 16); acc[5] += __uint_as_float((u).z & 0xffff0000u); \
    acc[6] += __uint_as_float((u).w << 16); acc[7] += __uint_as_float((u).w & 0xffff0000u); }
  int e = e0;
  for (; e+4 <= e1; e += 4) {
    int s0 = srclist[e], s1 = srclist[e+1], s2 = srclist[e+2], s3 = srclist[e+3];
    uint4 u0 = *(const uint4*)(xr + (size_t)s0*CH);
    uint4 u1 = *(const uint4*)(xr + (size_t)s1*CH);
    uint4 u2 = *(const uint4*)(xr + (size_t)s2*CH);
    uint4 u3 = *(const uint4*)(xr + (size_t)s3*CH);
    ADD8(A, u0) ADD8(B, u1) ADD8(C, u2) ADD8(D, u3)
  }
  for (; e < e1; ++e) {
    int s0 = srclist[e];
    uint4 u0 = *(const uint4*)(xr + (size_t)s0*CH);
    ADD8(A, u0)
  }
  #undef ADD8
  float ep = 1.0f + eps[layer];
  uint4 sv = *(const uint4*)(xr + (size_t)n*CH);
  float sf[8];
  sf[0] = __uint_as_float(sv.x << 16); sf[1] = __uint_as_float(sv.x & 0xffff0000u);
  sf[2] = __uint_as_float(sv.y << 16); sf[3] = __uint_as_float(sv.y & 0xffff0000u);
  sf[4] = __uint_as_float(sv.z << 16); sf[5] = __uint_as_float(sv.z & 0xffff0000u);
  sf[6] = __uint_as_float(sv.w << 16); sf[7] = __uint_as_float(sv.w & 0xffff0000u);
  float r[8];
  #pragma unroll
  for (int i = 0; i < 8; ++i) r[i] = fmaf(ep, sf[i], (A[i] + B[i]) + (C[i] + D[i]));
  float* tp = T + (size_t)n*CH + c;
  *(float4*)(tp)   = make_float4(r[0], r[1], r[2], r[3]);
  *(float4*)(tp+4) = make_float4(r[4], r[5], r[6], r[7]);
}

// ---- MLP: T -> (GEMM1+BN+ReLU) -> (GEMM2+BN+ReLU) -> outer BN; out bf16 (mode 1) or fp32 (mode 0) ----
__global__ __launch_bounds__(256) void mlp_kernel(const float* __restrict__ T, const float* __restrict__ Wf,
                                                  const float* __restrict__ bf, const float* __restrict__ ogb,
                                                  int layer, float* __restrict__ outf,
                                                  unsigned short* __restrict__ outb, int relu_out){
  __shared__ __align__(16) float Ws[64*64];     // W1, later W2
  __shared__ __align__(16) float Hs[64*68];     // +4 pad
  int tid = threadIdx.x;
  int b = blockIdx.x;
  const float* Wg = Wf + layer*8192;
  #pragma unroll
  for (int it = 0; it < 4; ++it) {
    int i = (tid + it*256) * 4;
    *(float4*)&Ws[i] = ld4(Wg + i);
  }
  long gbase = (long)b * 4096;
  #pragma unroll
  for (int it = 0; it < 4; ++it) {
    int idx = (tid + it*256) * 4;
    int nrow = idx >> 6, kk = idx & 63;
    float4 v = make_float4(0.f,0.f,0.f,0.f);
    if (gbase + idx < (long)N_NODES*CH) v = ld4(T + gbase + idx);
    *(float4*)&Hs[nrow*68 + kk] = v;
  }
  __syncthreads();

  int lq = tid & 15, jg = tid >> 4;
  int j0 = jg << 2;
  const float4 bias1 = ld4(bf + layer*128 + j0);
  const float4 bias2 = ld4(bf + layer*128 + 64 + j0);
  const float4 og4   = ld4(ogb + layer*64 + j0);
  const float4 ob4   = ld4(ogb + NLAYERS*64 + layer*64 + j0);

  float acc[4][4];
  #pragma unroll
  for (int r = 0; r < 4; ++r){ acc[r][0]=bias1.x; acc[r][1]=bias1.y; acc[r][2]=bias1.z; acc[r][3]=bias1.w; }

  for (int k = 0; k < 64; k += 4) {
    float4 a[4], bb[4];
    #pragma unroll
    for (int r = 0; r < 4; ++r) a[r] = *(const float4*)&Hs[(lq + 16*r)*68 + k];
    #pragma unroll
    for (int kk = 0; kk < 4; ++kk) bb[kk] = *(const float4*)&Ws[(k+kk)*64 + j0];
    #pragma unroll
    for (int r = 0; r < 4; ++r){
      const float* ar = (const float*)&a[r];
      #pragma unroll
      for (int kk = 0; kk < 4; ++kk){
        float av = ar[kk];
        acc[r][0] = fmaf(av, bb[kk].x, acc[r][0]);
        acc[r][1] = fmaf(av, bb[kk].y, acc[r][1]);
        acc[r][2] = fmaf(av, bb[kk].z, acc[r][2]);
        acc[r][3] = fmaf(av, bb[kk].w, acc[r][3]);
      }
    }
  }
  __syncthreads();   // GEMM1 reads of Hs & Ws done
  #pragma unroll
  for (int r = 0; r < 4; ++r){
    float4 hv = make_float4(fmaxf(acc[r][0],0.f), fmaxf(acc[r][1],0.f),
                            fmaxf(acc[r][2],0.f), fmaxf(acc[r][3],0.f));
    *(float4*)&Hs[(lq + 16*r)*68 + j0] = hv;
  }
  #pragma unroll
  for (int it = 0; it < 4; ++it) {
    int i = (tid + it*256) * 4;
    *(float4*)&Ws[i] = ld4(Wg + 4096 + i);    // W2 into the same buffer
  }
  __syncthreads();

  #pragma unroll
  for (int r = 0; r < 4; ++r){ acc[r][0]=bias2.x; acc[r][1]=bias2.y; acc[r][2]=bias2.z; acc[r][3]=bias2.w; }
  for (int k = 0; k < 64; k += 4) {
    float4 a[4], bb[4];
    #pragma unroll
    for (int r = 0; r < 4; ++r) a[r] = *(const float4*)&Hs[(lq + 16*r)*68 + k];
    #pragma unroll
    for (int kk = 0; kk < 4; ++kk) bb[kk] = *(const float4*)&Ws[(k+kk)*64 + j0];
    #pragma unroll
    for (int r = 0; r < 4; ++r){
      const float* ar = (const float*)&a[r];
      #pragma unroll
      for (int kk = 0; kk < 4; ++kk){
        float av = ar[kk];
        acc[r][0] = fmaf(av, bb[kk].x, acc[r][0]);
        acc[r][1] = fmaf(av, bb[kk].y, acc[r][1]);
        acc[r][2] = fmaf(av, bb[kk].z, acc[r][2]);
        acc[r][3] = fmaf(av, bb[kk].w, acc[r][3]);
      }
    }
  }

  #pragma unroll
  for (int r = 0; r < 4; ++r){
    int gnode = b*64 + lq + 16*r;
    if (gnode < N_NODES) {
      float o0 = fmaf(og4.x, fmaxf(acc[r][0],0.f), ob4.x);
      float o1 = fmaf(og4.y, fmaxf(acc[r][1],0.f), ob4.y);
      float o2 = fmaf(og4.z, fmaxf(acc[r][2],0.f), ob4.z);
      float o3 = fmaf(og4.w, fmaxf(acc[r][3],0.f), ob4.w);
      if (relu_out) {
        ushort4 w = make_ushort4(f2bf(fmaxf(o0,0.f)), f2bf(fmaxf(o1,0.f)),
                                 f2bf(fmaxf(o2,0.f)), f2bf(fmaxf(o3,0.f)));
        *(ushort4*)(outb + (size_t)gnode*CH + j0) = w;
      } else {
        *(float4*)(outf + (size_t)gnode*CH + j0) = make_float4(o0,o1,o2,o3);
      }
    }
  }
}

extern "C" void kernel_launch(void* const* d_in, const int* in_sizes, int n_in,
                              void* d_out, int out_size, void* d_ws, size_t ws_size,
                              hipStream_t stream) {
  const float* x0  = (const float*)d_in[0];
  const int*   ei  = (const int*)d_in[1];
  const float* eps = (const float*)d_in[2];
  const float* W1  = (const float*)d_in[3];
  const float* b1  = (const float*)d_in[4];
  const float* g1  = (const float*)d_in[5];
  const float* be1 = (const float*)d_in[6];
  const float* W2  = (const float*)d_in[7];
  const float* b2  = (const float*)d_in[8];
  const float* g2  = (const float*)d_in[9];
  const float* be2 = (const float*)d_in[10];
  const float* bng = (const float*)d_in[11];
  const float* bnb = (const float*)d_in[12];
  const int* src = ei;
  const int* dst = ei + N_EDGES;
  float* OUT = (float*)d_out;

  char* p = (char*)d_ws;
  auto carve = [&](size_t bytes)->char*{ char* r = p; p += (bytes + 255) & ~(size_t)255; return r; };
  int*   offs    = (int*)carve((size_t)N_NODES*sizeof(int));
  int*   offe    = (int*)carve((size_t)N_NODES*sizeof(int));
  int*   btail   = (int*)carve(NBUCK*sizeof(int));
  // pairs (16.0 MB slabs) dead after csr_kernel; T (25.6 MB fp32) aliases the same region.
  char*  big     = carve((size_t)N_NODES*CH*sizeof(float));   // 25.6 MB
  int2*  pairs   = (int2*)big;
  float* T       = (float*)big;
  unsigned short* XB = (unsigned short*)carve((size_t)N_NODES*CH*sizeof(unsigned short)); // 12.8 MB
  int*   srclist = (int*)carve((size_t)NBUCK*SLAB*sizeof(int));   // 8.0 MB (slab layout)
  float* Wf      = (float*)carve((size_t)NLAYERS*2*4096*sizeof(float));
  float* bfb     = (float*)carve((size_t)NLAYERS*2*64*sizeof(float));
  float* ogb     = (float*)carve((size_t)2*NLAYERS*64*sizeof(float));

  const int npart = (N_EDGES + EPB - 1)/EPB;   // 782
  binit_kernel<<<(NBUCK+255)/256, 256, 0, stream>>>(btail);
  part_kernel<<<npart, 256, 0, stream>>>(src, dst, btail, pairs);
  csr_kernel<<<NBUCK, 512, 0, stream>>>(pairs, btail, offs, offe, srclist);
  prep_kernel<<<48, 256, 0, stream>>>(W1,b1,g1,be1,W2,b2,g2,be2,bng,bnb,Wf,bfb,ogb);
  xcvt_kernel<<<(N_NODES*CH/4 + 255)/256, 256, 0, stream>>>(x0, XB);

  const int nab = (N_NODES*8 + 255)/256;    // 3125
  const int nmb = (N_NODES + 63)/64;        // 1563
  for (int l = 0; l < NLAYERS; ++l) {
    agg_kernel<<<nab, 256, 0, stream>>>(XB, offs, offe, srclist, eps, l, T);
    mlp_kernel<<<nmb, 256, 0, stream>>>(T, Wf, bfb, ogb, l, OUT, XB, (l < NLAYERS-1) ? 1 : 0);
  }
}

// Round 7
// 348.185 us; speedup vs baseline: 5.8445x; 1.0070x over previous
//
#include <hip/hip_runtime.h>
#include <hip/hip_fp16.h>

#define N_NODES 100000
#define N_EDGES 1600000
#define CH 64
#define NLAYERS 3
#define NBUCK 782          // buckets of 128 dst nodes (NBUCK*128 = 100096)
#define SLAB 2560          // slab capacity (mean 2046, sd 45 -> +11 sigma)
#define EPB 1024           // edges per partition block (1563 blocks)
#define STASH 10

typedef _Float16 half8 __attribute__((ext_vector_type(8)));
typedef float floatx4 __attribute__((ext_vector_type(4)));

static __device__ __forceinline__ float4 ld4(const float* p){ return *(const float4*)p; }
static __device__ __forceinline__ unsigned pack2(float a, float b){
  __half2 h = __float22half2_rn(make_float2(a, b));
  return *(unsigned*)&h;
}
static __device__ __forceinline__ float2 up2(unsigned u){
  __half2 h = *(__half2*)&u;
  return __half22float2(h);
}

// ---- btail init: slab base cursors ----
__global__ __launch_bounds__(256) void binit_kernel(int* __restrict__ btail){
  int i = blockIdx.x*256 + threadIdx.x;
  if (i < NBUCK) btail[i] = i*SLAB;
}

// ---- partition edges into per-bucket slabs: psrc (int) + pdl (u8 local dst) ----
__global__ __launch_bounds__(256) void part_kernel(const int* __restrict__ src, const int* __restrict__ dst,
                                                   int* __restrict__ btail,
                                                   int* __restrict__ psrc, unsigned char* __restrict__ pdl){
  __shared__ int lpos[NBUCK];
  __shared__ int gb[NBUCK];
  int tid = threadIdx.x;
  for (int i = tid; i < NBUCK; i += 256) lpos[i] = 0;
  __syncthreads();
  int base = blockIdx.x * EPB;
  int es[4], ed[4], er[4];
  #pragma unroll
  for (int k = 0; k < 4; ++k) {
    int e = base + k*256 + tid;
    if (e < N_EDGES) {
      es[k] = src[e];
      ed[k] = dst[e];
      er[k] = atomicAdd(&lpos[ed[k] >> 7], 1);
    }
  }
  __syncthreads();
  for (int i = tid; i < NBUCK; i += 256) {
    int cc = lpos[i];
    gb[i] = cc ? atomicAdd(&btail[i], cc) : 0;
  }
  __syncthreads();
  #pragma unroll
  for (int k = 0; k < 4; ++k) {
    int e = base + k*256 + tid;
    if (e < N_EDGES) {
      int bk = ed[k] >> 7;
      int idx = gb[bk] + er[k];
      if (idx < (bk+1)*SLAB) {                  // memory-safety clamp (statistically never)
        psrc[idx] = es[k];
        pdl[idx] = (unsigned char)(ed[k] & 127);
      }
    }
  }
}

// ---- per-bucket CSR build: offs/offe + srclist (slab layout) ----
__global__ __launch_bounds__(256) void csr_kernel(const int* __restrict__ psrc, const unsigned char* __restrict__ pdl,
                                                  const int* __restrict__ btail,
                                                  int* __restrict__ offs, int* __restrict__ offe,
                                                  int* __restrict__ srclist){
  __shared__ int c[128];
  __shared__ int s[128];
  __shared__ int cur[128];
  int t = threadIdx.x;
  int b = blockIdx.x;
  int e0 = b*SLAB;
  int e1 = btail[b]; int emax = e0 + SLAB; if (e1 > emax) e1 = emax;
  if (t < 128) c[t] = 0;
  __syncthreads();
  int ss[STASH]; int dd[STASH];
  int k = 0;
  for (int i = e0 + t; i < e1; i += 256, ++k) {
    int sv = psrc[i];
    int dl = pdl[i];
    if (k < STASH) { ss[k] = sv; dd[k] = dl; }
    atomicAdd(&c[dl], 1);
  }
  __syncthreads();
  int v = (t < 128) ? c[t] : 0;
  if (t < 128) s[t] = v;
  __syncthreads();
  #pragma unroll
  for (int o = 1; o < 128; o <<= 1){
    int u = 0;
    if (t < 128 && t >= o) u = s[t-o];
    __syncthreads();
    if (t < 128) s[t] += u;
    __syncthreads();
  }
  if (t < 128) {
    int excl = s[t] - v;
    cur[t] = excl;
    int n = b*128 + t;
    if (n < N_NODES) { offs[n] = e0 + excl; offe[n] = e0 + excl + v; }
  }
  __syncthreads();
  k = 0;
  for (int i = e0 + t; i < e1; i += 256, ++k) {
    int sv, dl;
    if (k < STASH) { sv = ss[k]; dl = dd[k]; } else { sv = psrc[i]; dl = pdl[i]; }
    int p = atomicAdd(&cur[dl], 1);
    srclist[e0 + p] = sv;
  }
}

// ---- fold BN into weights (fp16, transposed, XOR-swizzled) and biases (fp32) ----
// Wt layout: [L][2][ n*64 + ((k>>3)^(n&7))*8 + (k&7) ]  holding W[k][n]*g[n]*s
__global__ __launch_bounds__(256) void prep_kernel(
    const float* __restrict__ W1, const float* __restrict__ b1,
    const float* __restrict__ g1, const float* __restrict__ be1,
    const float* __restrict__ W2, const float* __restrict__ b2,
    const float* __restrict__ g2, const float* __restrict__ be2,
    const float* __restrict__ bng, const float* __restrict__ bnb,
    _Float16* __restrict__ Wt, float* __restrict__ bf, float* __restrict__ ogb){
  const float s = 0.9999950000374997f;   // 1/sqrt(1+1e-5)
  int i = blockIdx.x*256 + threadIdx.x;
  if (i < NLAYERS*4096) {
    int l = i >> 12, rem = i & 4095, k = rem >> 6, n = rem & 63;
    int di = n*64 + (((k>>3) ^ (n&7))<<3) + (k&7);
    Wt[l*8192 + di]        = (_Float16)(W1[i] * g1[l*64+n] * s);
    Wt[l*8192 + 4096 + di] = (_Float16)(W2[i] * g2[l*64+n] * s);
  }
  if (i < NLAYERS*64) {
    int l = i >> 6, j = i & 63;
    bf[l*128 + j]      = b1[i]*g1[i]*s + be1[i];
    bf[l*128 + 64 + j] = b2[i]*g2[i]*s + be2[i];
    ogb[i]                 = bng[i]*s;
    ogb[NLAYERS*64 + i]    = bnb[i];
  }
}

// ---- x0 (fp32) -> XB (fp16) ----
__global__ __launch_bounds__(256) void xcvt_kernel(const float* __restrict__ x, unsigned short* __restrict__ xb){
  int i = (blockIdx.x*256 + threadIdx.x)*8;
  if (i < N_NODES*CH) {
    float4 v0 = ld4(x + i), v1 = ld4(x + i + 4);
    uint4 w;
    w.x = pack2(v0.x, v0.y); w.y = pack2(v0.z, v0.w);
    w.z = pack2(v1.x, v1.y); w.w = pack2(v1.z, v1.w);
    *(uint4*)(xb + i) = w;
  }
}

// ---- aggregation: 8 lanes/node, 8 ch/lane (uint4 = 8 fp16), 4 independent chains; T out fp16 ----
__global__ __launch_bounds__(256) void agg_kernel(const unsigned short* __restrict__ xb,
                                                  const int* __restrict__ offs, const int* __restrict__ offe,
                                                  const int* __restrict__ srclist,
                                                  const float* __restrict__ eps, int layer,
                                                  unsigned short* __restrict__ T){
  int g = blockIdx.x*256 + threadIdx.x;
  int n = g >> 3;
  if (n >= N_NODES) return;
  int c = (g & 7) << 3;
  const unsigned short* xr = xb + c;
  int e0 = offs[n], e1 = offe[n];
  float A[8] = {0,0,0,0,0,0,0,0};
  float B[8] = {0,0,0,0,0,0,0,0};
  float C[8] = {0,0,0,0,0,0,0,0};
  float D[8] = {0,0,0,0,0,0,0,0};
  #define ADD8(acc, u) { float2 f; \
    f = up2((u).x); acc[0] += f.x; acc[1] += f.y; \
    f = up2((u).y); acc[2] += f.x; acc[3] += f.y; \
    f = up2((u).z); acc[4] += f.x; acc[5] += f.y; \
    f = up2((u).w); acc[6] += f.x; acc[7] += f.y; }
  int e = e0;
  for (; e+4 <= e1; e += 4) {
    int s0 = srclist[e], s1 = srclist[e+1], s2 = srclist[e+2], s3 = srclist[e+3];
    uint4 u0 = *(const uint4*)(xr + (size_t)s0*CH);
    uint4 u1 = *(const uint4*)(xr + (size_t)s1*CH);
    uint4 u2 = *(const uint4*)(xr + (size_t)s2*CH);
    uint4 u3 = *(const uint4*)(xr + (size_t)s3*CH);
    ADD8(A, u0) ADD8(B, u1) ADD8(C, u2) ADD8(D, u3)
  }
  for (; e < e1; ++e) {
    int s0 = srclist[e];
    uint4 u0 = *(const uint4*)(xr + (size_t)s0*CH);
    ADD8(A, u0)
  }
  #undef ADD8
  float ep = 1.0f + eps[layer];
  uint4 sv = *(const uint4*)(xr + (size_t)n*CH);
  float sf[8];
  { float2 f;
    f = up2(sv.x); sf[0]=f.x; sf[1]=f.y;
    f = up2(sv.y); sf[2]=f.x; sf[3]=f.y;
    f = up2(sv.z); sf[4]=f.x; sf[5]=f.y;
    f = up2(sv.w); sf[6]=f.x; sf[7]=f.y; }
  float r[8];
  #pragma unroll
  for (int i = 0; i < 8; ++i) r[i] = fmaf(ep, sf[i], (A[i] + B[i]) + (C[i] + D[i]));
  uint4 w;
  w.x = pack2(r[0], r[1]); w.y = pack2(r[2], r[3]);
  w.z = pack2(r[4], r[5]); w.w = pack2(r[6], r[7]);
  *(uint4*)(T + (size_t)n*CH + c) = w;
}

// ---- MFMA MLP: T(fp16) -> GEMM1+BN+ReLU -> GEMM2+BN+ReLU -> outer BN; out fp16 XB or fp32 OUT ----
// 64 nodes/block, 4 waves; wave w owns rows 16w..16w+15; 4 n-tiles x 2 k-steps of 16x16x32 f16 MFMA.
// LDS fp16 rows of 64 with k-block XOR swizzle (block kb at kb^(m&7)): A/B b128 reads & staging <=2-way.
__global__ __launch_bounds__(256) void mlp_kernel(const unsigned short* __restrict__ T,
                                                  const _Float16* __restrict__ Wt,
                                                  const float* __restrict__ bf, const float* __restrict__ ogb,
                                                  int layer, float* __restrict__ outf,
                                                  _Float16* __restrict__ outb, int relu_out){
  __shared__ _Float16 HsA[64*64];
  __shared__ _Float16 Wts[64*64];
  int tid = threadIdx.x;
  int b = blockIdx.x;
  const _Float16* Wg = Wt + layer*8192;
  *(uint4*)&Wts[tid*8]       = *(const uint4*)&Wg[tid*8];
  *(uint4*)&Wts[(tid+256)*8] = *(const uint4*)&Wg[(tid+256)*8];
  #pragma unroll
  for (int it = 0; it < 2; ++it) {
    int t2 = tid + it*256;         // 0..511
    int m = t2 >> 3, kb = t2 & 7;
    int gnode = b*64 + m;
    uint4 v = make_uint4(0,0,0,0);
    if (gnode < N_NODES) v = *(const uint4*)&T[(size_t)gnode*CH + kb*8];
    *(uint4*)&HsA[m*64 + ((kb ^ (m&7))<<3)] = v;
  }
  __syncthreads();

  int lane = tid & 63;
  int wid = tid >> 6;
  int c = lane & 15;
  int q = lane >> 4;
  int mbase = wid*16;
  int ma = mbase + c;            // A-fragment row for this lane

  half8 a0 = *(const half8*)&HsA[ma*64 + (((q)   ^ (ma&7))<<3)];
  half8 a1 = *(const half8*)&HsA[ma*64 + (((4+q) ^ (ma&7))<<3)];

  floatx4 acc[4];
  #pragma unroll
  for (int nt = 0; nt < 4; ++nt) {
    int n = nt*16 + c;
    float bv = bf[layer*128 + n];
    floatx4 A = {bv, bv, bv, bv};
    half8 b0 = *(const half8*)&Wts[n*64 + (((q)   ^ (n&7))<<3)];
    half8 b1 = *(const half8*)&Wts[n*64 + (((4+q) ^ (n&7))<<3)];
    A = __builtin_amdgcn_mfma_f32_16x16x32_f16(a0, b0, A, 0, 0, 0);
    A = __builtin_amdgcn_mfma_f32_16x16x32_f16(a1, b1, A, 0, 0, 0);
    acc[nt] = A;
  }
  __syncthreads();   // all GEMM1 LDS reads complete

  // H2 = relu(GEMM1) back into HsA (C/D layout: col=lane&15 -> n, row=q*4+r -> m)
  #pragma unroll
  for (int nt = 0; nt < 4; ++nt) {
    int n = nt*16 + c;
    #pragma unroll
    for (int r = 0; r < 4; ++r) {
      int m = mbase + q*4 + r;
      float h = acc[nt][r]; h = h > 0.f ? h : 0.f;
      HsA[m*64 + (((n>>3) ^ (m&7))<<3) + (n&7)] = (_Float16)h;
    }
  }
  *(uint4*)&Wts[tid*8]       = *(const uint4*)&Wg[4096 + tid*8];       // W2t
  *(uint4*)&Wts[(tid+256)*8] = *(const uint4*)&Wg[4096 + (tid+256)*8];
  __syncthreads();

  half8 c0 = *(const half8*)&HsA[ma*64 + (((q)   ^ (ma&7))<<3)];
  half8 c1 = *(const half8*)&HsA[ma*64 + (((4+q) ^ (ma&7))<<3)];
  floatx4 acc2[4];
  #pragma unroll
  for (int nt = 0; nt < 4; ++nt) {
    int n = nt*16 + c;
    float bv = bf[layer*128 + 64 + n];
    floatx4 A = {bv, bv, bv, bv};
    half8 b0 = *(const half8*)&Wts[n*64 + (((q)   ^ (n&7))<<3)];
    half8 b1 = *(const half8*)&Wts[n*64 + (((4+q) ^ (n&7))<<3)];
    A = __builtin_amdgcn_mfma_f32_16x16x32_f16(c0, b0, A, 0, 0, 0);
    A = __builtin_amdgcn_mfma_f32_16x16x32_f16(c1, b1, A, 0, 0, 0);
    acc2[nt] = A;
  }

  #pragma unroll
  for (int nt = 0; nt < 4; ++nt) {
    int n = nt*16 + c;
    float og = ogb[layer*64 + n];
    float ob = ogb[NLAYERS*64 + layer*64 + n];
    #pragma unroll
    for (int r = 0; r < 4; ++r) {
      int m = mbase + q*4 + r;
      int gnode = b*64 + m;
      if (gnode < N_NODES) {
        float h = acc2[nt][r]; h = h > 0.f ? h : 0.f;
        float o = fmaf(og, h, ob);
        if (relu_out) {
          o = o > 0.f ? o : 0.f;
          outb[(size_t)gnode*CH + n] = (_Float16)o;
        } else {
          outf[(size_t)gnode*CH + n] = o;
        }
      }
    }
  }
}

extern "C" void kernel_launch(void* const* d_in, const int* in_sizes, int n_in,
                              void* d_out, int out_size, void* d_ws, size_t ws_size,
                              hipStream_t stream) {
  const float* x0  = (const float*)d_in[0];
  const int*   ei  = (const int*)d_in[1];
  const float* eps = (const float*)d_in[2];
  const float* W1  = (const float*)d_in[3];
  const float* b1  = (const float*)d_in[4];
  const float* g1  = (const float*)d_in[5];
  const float* be1 = (const float*)d_in[6];
  const float* W2  = (const float*)d_in[7];
  const float* b2  = (const float*)d_in[8];
  const float* g2  = (const float*)d_in[9];
  const float* be2 = (const float*)d_in[10];
  const float* bng = (const float*)d_in[11];
  const float* bnb = (const float*)d_in[12];
  const int* src = ei;
  const int* dst = ei + N_EDGES;
  float* OUT = (float*)d_out;

  char* p = (char*)d_ws;
  auto carve = [&](size_t bytes)->char*{ char* r = p; p += (bytes + 255) & ~(size_t)255; return r; };
  int*   offs    = (int*)carve((size_t)N_NODES*sizeof(int));
  int*   offe    = (int*)carve((size_t)N_NODES*sizeof(int));
  int*   btail   = (int*)carve(NBUCK*sizeof(int));
  int*   psrc    = (int*)carve((size_t)NBUCK*SLAB*sizeof(int));          // 8.0 MB
  unsigned char* pdl = (unsigned char*)carve((size_t)NBUCK*SLAB);        // 2.0 MB
  int*   srclist = (int*)carve((size_t)NBUCK*SLAB*sizeof(int));          // 8.0 MB
  unsigned short* T  = (unsigned short*)carve((size_t)N_NODES*CH*2);     // 12.8 MB fp16
  unsigned short* XB = (unsigned short*)carve((size_t)N_NODES*CH*2);     // 12.8 MB fp16
  _Float16* Wt   = (_Float16*)carve((size_t)NLAYERS*2*4096*2);
  float* bfb     = (float*)carve((size_t)NLAYERS*2*64*sizeof(float));
  float* ogb     = (float*)carve((size_t)2*NLAYERS*64*sizeof(float));

  const int npart = (N_EDGES + EPB - 1)/EPB;   // 1563
  binit_kernel<<<(NBUCK+255)/256, 256, 0, stream>>>(btail);
  part_kernel<<<npart, 256, 0, stream>>>(src, dst, btail, psrc, pdl);
  csr_kernel<<<NBUCK, 256, 0, stream>>>(psrc, pdl, btail, offs, offe, srclist);
  prep_kernel<<<48, 256, 0, stream>>>(W1,b1,g1,be1,W2,b2,g2,be2,bng,bnb,Wt,bfb,ogb);
  xcvt_kernel<<<(N_NODES*CH/8 + 255)/256, 256, 0, stream>>>(x0, XB);

  const int nab = (N_NODES*8 + 255)/256;    // 3125
  const int nmb = (N_NODES + 63)/64;        // 1563
  for (int l = 0; l < NLAYERS; ++l) {
    agg_kernel<<<nab, 256, 0, stream>>>(XB, offs, offe, srclist, eps, l, T);
    mlp_kernel<<<nmb, 256, 0, stream>>>(T, Wt, bfb, ogb, l, OUT, (_Float16*)XB, (l < NLAYERS-1) ? 1 : 0);
  }
}

// Round 8
// 322.182 us; speedup vs baseline: 6.3162x; 1.0807x over previous
//
#include <hip/hip_runtime.h>
#include <hip/hip_fp16.h>

#define N_NODES 100000
#define N_EDGES 1600000
#define CH 64
#define NLAYERS 3
#define NBUCKC 98          // coarse buckets of 1024 dst nodes
#define SLABC 18432        // slab capacity (mean 16327, sd 127 -> +16 sigma)
#define SUBCAP 2304        // per-128-node sub-slab capacity (mean 2048, sd 45; 8*SUBCAP==SLABC)
#define EPB 8192           // edges per partition block (196 blocks)

typedef _Float16 half8 __attribute__((ext_vector_type(8)));
typedef float floatx4 __attribute__((ext_vector_type(4)));

static __device__ __forceinline__ float4 ld4(const float* p){ return *(const float4*)p; }
static __device__ __forceinline__ unsigned pack2(float a, float b){
  __half2 h = __float22half2_rn(make_float2(a, b));
  return *(unsigned*)&h;
}
static __device__ __forceinline__ float2 up2(unsigned u){
  __half2 h = *(__half2*)&u;
  return __half22float2(h);
}

// ---- btail init: slab base cursors ----
__global__ __launch_bounds__(256) void binit_kernel(int* __restrict__ btail){
  int i = blockIdx.x*256 + threadIdx.x;
  if (i < NBUCKC) btail[i] = i*SLABC;
}

// ---- partition edges into 98 coarse slabs; packed pair = src | ((dst&1023)<<20) ----
// Two rounds over the block's edge range (2nd read is L1/L2-hot): count -> reserve -> place.
// Chunk per (block,bucket) ~84 edges = ~5 full lines -> line-dense writes.
__global__ __launch_bounds__(256) void part_kernel(const int* __restrict__ src, const int* __restrict__ dst,
                                                   int* __restrict__ btail, int* __restrict__ pairs){
  __shared__ int lpos[NBUCKC];
  __shared__ int gb[NBUCKC];
  int tid = threadIdx.x;
  if (tid < NBUCKC) lpos[tid] = 0;
  __syncthreads();
  int base = blockIdx.x * EPB;
  #pragma unroll 4
  for (int k = 0; k < EPB/256; ++k) {
    int e = base + k*256 + tid;
    if (e < N_EDGES) atomicAdd(&lpos[dst[e] >> 10], 1);
  }
  __syncthreads();
  if (tid < NBUCKC) {
    int cc = lpos[tid];
    gb[tid] = cc ? atomicAdd(&btail[tid], cc) : 0;
    lpos[tid] = 0;
  }
  __syncthreads();
  #pragma unroll 4
  for (int k = 0; k < EPB/256; ++k) {
    int e = base + k*256 + tid;
    if (e < N_EDGES) {
      int d = dst[e];
      int bk = d >> 10;
      int p = atomicAdd(&lpos[bk], 1);
      int idx = gb[bk] + p;
      if (idx < (bk+1)*SLABC)                   // memory-safety clamp (statistically never)
        pairs[idx] = src[e] | ((d & 1023) << 20);
    }
  }
}

// ---- CSR build: 8 blocks per coarse slab, each owns a 128-node sub-range ----
// Block reads the whole slab, filters its 1/8, LDS hist/scan/scatter into its private sub-slab.
__global__ __launch_bounds__(256) void csr_kernel(const int* __restrict__ pairs, const int* __restrict__ btail,
                                                  int* __restrict__ offs, int* __restrict__ offe,
                                                  int* __restrict__ srclist){
  __shared__ int c[128];
  __shared__ int s[128];
  __shared__ int cur[128];
  int t = threadIdx.x;
  int b = blockIdx.x >> 3;
  int j = blockIdx.x & 7;
  int e0 = b*SLABC;
  int e1 = btail[b]; int emax = e0 + SLABC; if (e1 > emax) e1 = emax;
  if (t < 128) c[t] = 0;
  __syncthreads();
  for (int i = e0 + t; i < e1; i += 256) {
    int p = pairs[i];
    int dl = (unsigned)p >> 20;
    if ((dl >> 7) == j) atomicAdd(&c[dl & 127], 1);
  }
  __syncthreads();
  int v = (t < 128) ? c[t] : 0;
  if (t < 128) s[t] = v;
  __syncthreads();
  #pragma unroll
  for (int o = 1; o < 128; o <<= 1){
    int u = 0;
    if (t < 128 && t >= o) u = s[t-o];
    __syncthreads();
    if (t < 128) s[t] += u;
    __syncthreads();
  }
  int base = e0 + j*SUBCAP;
  if (t < 128) {
    int excl = s[t] - v;
    cur[t] = excl;
    int n = b*1024 + j*128 + t;
    if (n < N_NODES) { offs[n] = base + excl; offe[n] = base + excl + v; }
  }
  __syncthreads();
  for (int i = e0 + t; i < e1; i += 256) {
    int p = pairs[i];
    int dl = (unsigned)p >> 20;
    if ((dl >> 7) == j) {
      int pos = atomicAdd(&cur[dl & 127], 1);
      if (pos < SUBCAP)                          // memory-safety clamp
        srclist[base + pos] = p & 0xFFFFF;
    }
  }
}

// ---- fold BN into weights (fp16, transposed, XOR-swizzled) and biases (fp32) ----
// Wt layout: [L][2][ n*64 + ((k>>3)^(n&7))*8 + (k&7) ]  holding W[k][n]*g[n]*s
__global__ __launch_bounds__(256) void prep_kernel(
    const float* __restrict__ W1, const float* __restrict__ b1,
    const float* __restrict__ g1, const float* __restrict__ be1,
    const float* __restrict__ W2, const float* __restrict__ b2,
    const float* __restrict__ g2, const float* __restrict__ be2,
    const float* __restrict__ bng, const float* __restrict__ bnb,
    _Float16* __restrict__ Wt, float* __restrict__ bf, float* __restrict__ ogb){
  const float s = 0.9999950000374997f;   // 1/sqrt(1+1e-5)
  int i = blockIdx.x*256 + threadIdx.x;
  if (i < NLAYERS*4096) {
    int l = i >> 12, rem = i & 4095, k = rem >> 6, n = rem & 63;
    int di = n*64 + (((k>>3) ^ (n&7))<<3) + (k&7);
    Wt[l*8192 + di]        = (_Float16)(W1[i] * g1[l*64+n] * s);
    Wt[l*8192 + 4096 + di] = (_Float16)(W2[i] * g2[l*64+n] * s);
  }
  if (i < NLAYERS*64) {
    int l = i >> 6, j = i & 63;
    bf[l*128 + j]      = b1[i]*g1[i]*s + be1[i];
    bf[l*128 + 64 + j] = b2[i]*g2[i]*s + be2[i];
    ogb[i]                 = bng[i]*s;
    ogb[NLAYERS*64 + i]    = bnb[i];
  }
}

// ---- x0 (fp32) -> XB0 (fp16) ----
__global__ __launch_bounds__(256) void xcvt_kernel(const float* __restrict__ x, unsigned short* __restrict__ xb){
  int i = (blockIdx.x*256 + threadIdx.x)*8;
  if (i < N_NODES*CH) {
    float4 v0 = ld4(x + i), v1 = ld4(x + i + 4);
    uint4 w;
    w.x = pack2(v0.x, v0.y); w.y = pack2(v0.z, v0.w);
    w.z = pack2(v1.x, v1.y); w.w = pack2(v1.z, v1.w);
    *(uint4*)(xb + i) = w;
  }
}

// ---- fused layer: gather-agg straight into LDS H (no atomics) -> MFMA MLP -> epilogue ----
// 64 nodes/block, 256 threads, 16 KB LDS. Gather: 8 lanes/node, 8ch/lane, 4 chains, 2 passes.
// Reads XBin, writes XBout (different buffers: ping-pong) or fp32 OUT at the last layer.
__global__ __launch_bounds__(256) void layer_kernel(const unsigned short* __restrict__ XBin,
                                                    const int* __restrict__ offs, const int* __restrict__ offe,
                                                    const int* __restrict__ srclist,
                                                    const float* __restrict__ eps,
                                                    const _Float16* __restrict__ Wt,
                                                    const float* __restrict__ bf, const float* __restrict__ ogb,
                                                    int layer, float* __restrict__ outf,
                                                    _Float16* __restrict__ outb, int relu_out){
  __shared__ _Float16 HsA[64*64];
  __shared__ _Float16 Wts[64*64];
  int tid = threadIdx.x;
  int b = blockIdx.x;
  const _Float16* Wg = Wt + layer*8192;
  *(uint4*)&Wts[tid*8]       = *(const uint4*)&Wg[tid*8];
  *(uint4*)&Wts[(tid+256)*8] = *(const uint4*)&Wg[(tid+256)*8];

  // gather phase: thread serves (node nl, channels 8*kb..8*kb+7); 2 passes of 32 nodes
  float ep = 1.0f + eps[layer];
  int kb = tid & 7;
  const unsigned short* xr = XBin + (kb << 3);
  #pragma unroll
  for (int p = 0; p < 2; ++p) {
    int nl = p*32 + (tid >> 3);
    int n = b*64 + nl;
    float A[8] = {0,0,0,0,0,0,0,0};
    float B[8] = {0,0,0,0,0,0,0,0};
    float C[8] = {0,0,0,0,0,0,0,0};
    float D[8] = {0,0,0,0,0,0,0,0};
    float r[8] = {0,0,0,0,0,0,0,0};
    if (n < N_NODES) {
      #define ADD8(acc, u) { float2 f; \
        f = up2((u).x); acc[0] += f.x; acc[1] += f.y; \
        f = up2((u).y); acc[2] += f.x; acc[3] += f.y; \
        f = up2((u).z); acc[4] += f.x; acc[5] += f.y; \
        f = up2((u).w); acc[6] += f.x; acc[7] += f.y; }
      int e0 = offs[n], e1 = offe[n];
      int e = e0;
      for (; e+4 <= e1; e += 4) {
        int s0 = srclist[e], s1 = srclist[e+1], s2 = srclist[e+2], s3 = srclist[e+3];
        uint4 u0 = *(const uint4*)(xr + (size_t)s0*CH);
        uint4 u1 = *(const uint4*)(xr + (size_t)s1*CH);
        uint4 u2 = *(const uint4*)(xr + (size_t)s2*CH);
        uint4 u3 = *(const uint4*)(xr + (size_t)s3*CH);
        ADD8(A, u0) ADD8(B, u1) ADD8(C, u2) ADD8(D, u3)
      }
      for (; e < e1; ++e) {
        int s0 = srclist[e];
        uint4 u0 = *(const uint4*)(xr + (size_t)s0*CH);
        ADD8(A, u0)
      }
      #undef ADD8
      uint4 sv = *(const uint4*)(xr + (size_t)n*CH);
      float sf[8];
      { float2 f;
        f = up2(sv.x); sf[0]=f.x; sf[1]=f.y;
        f = up2(sv.y); sf[2]=f.x; sf[3]=f.y;
        f = up2(sv.z); sf[4]=f.x; sf[5]=f.y;
        f = up2(sv.w); sf[6]=f.x; sf[7]=f.y; }
      #pragma unroll
      for (int i = 0; i < 8; ++i) r[i] = fmaf(ep, sf[i], (A[i] + B[i]) + (C[i] + D[i]));
    }
    uint4 w;
    w.x = pack2(r[0], r[1]); w.y = pack2(r[2], r[3]);
    w.z = pack2(r[4], r[5]); w.w = pack2(r[6], r[7]);
    *(uint4*)&HsA[nl*64 + ((kb ^ (nl&7))<<3)] = w;
  }
  __syncthreads();

  int lane = tid & 63;
  int wid = tid >> 6;
  int c = lane & 15;
  int q = lane >> 4;
  int mbase = wid*16;
  int ma = mbase + c;

  half8 a0 = *(const half8*)&HsA[ma*64 + (((q)   ^ (ma&7))<<3)];
  half8 a1 = *(const half8*)&HsA[ma*64 + (((4+q) ^ (ma&7))<<3)];

  floatx4 acc[4];
  #pragma unroll
  for (int nt = 0; nt < 4; ++nt) {
    int n = nt*16 + c;
    float bv = bf[layer*128 + n];
    floatx4 Acc = {bv, bv, bv, bv};
    half8 b0 = *(const half8*)&Wts[n*64 + (((q)   ^ (n&7))<<3)];
    half8 b1 = *(const half8*)&Wts[n*64 + (((4+q) ^ (n&7))<<3)];
    Acc = __builtin_amdgcn_mfma_f32_16x16x32_f16(a0, b0, Acc, 0, 0, 0);
    Acc = __builtin_amdgcn_mfma_f32_16x16x32_f16(a1, b1, Acc, 0, 0, 0);
    acc[nt] = Acc;
  }
  __syncthreads();   // all GEMM1 LDS reads complete

  // H2 = relu(GEMM1) back into HsA (C/D layout: col=lane&15 -> n, row=q*4+r -> m)
  #pragma unroll
  for (int nt = 0; nt < 4; ++nt) {
    int n = nt*16 + c;
    #pragma unroll
    for (int r = 0; r < 4; ++r) {
      int m = mbase + q*4 + r;
      float h = acc[nt][r]; h = h > 0.f ? h : 0.f;
      HsA[m*64 + (((n>>3) ^ (m&7))<<3) + (n&7)] = (_Float16)h;
    }
  }
  *(uint4*)&Wts[tid*8]       = *(const uint4*)&Wg[4096 + tid*8];       // W2t
  *(uint4*)&Wts[(tid+256)*8] = *(const uint4*)&Wg[4096 + (tid+256)*8];
  __syncthreads();

  half8 c0 = *(const half8*)&HsA[ma*64 + (((q)   ^ (ma&7))<<3)];
  half8 c1 = *(const half8*)&HsA[ma*64 + (((4+q) ^ (ma&7))<<3)];
  floatx4 acc2[4];
  #pragma unroll
  for (int nt = 0; nt < 4; ++nt) {
    int n = nt*16 + c;
    float bv = bf[layer*128 + 64 + n];
    floatx4 Acc = {bv, bv, bv, bv};
    half8 b0 = *(const half8*)&Wts[n*64 + (((q)   ^ (n&7))<<3)];
    half8 b1 = *(const half8*)&Wts[n*64 + (((4+q) ^ (n&7))<<3)];
    Acc = __builtin_amdgcn_mfma_f32_16x16x32_f16(c0, b0, Acc, 0, 0, 0);
    Acc = __builtin_amdgcn_mfma_f32_16x16x32_f16(c1, b1, Acc, 0, 0, 0);
    acc2[nt] = Acc;
  }

  #pragma unroll
  for (int nt = 0; nt < 4; ++nt) {
    int n = nt*16 + c;
    float og = ogb[layer*64 + n];
    float ob = ogb[NLAYERS*64 + layer*64 + n];
    #pragma unroll
    for (int r = 0; r < 4; ++r) {
      int m = mbase + q*4 + r;
      int gnode = b*64 + m;
      if (gnode < N_NODES) {
        float h = acc2[nt][r]; h = h > 0.f ? h : 0.f;
        float o = fmaf(og, h, ob);
        if (relu_out) {
          o = o > 0.f ? o : 0.f;
          outb[(size_t)gnode*CH + n] = (_Float16)o;
        } else {
          outf[(size_t)gnode*CH + n] = o;
        }
      }
    }
  }
}

extern "C" void kernel_launch(void* const* d_in, const int* in_sizes, int n_in,
                              void* d_out, int out_size, void* d_ws, size_t ws_size,
                              hipStream_t stream) {
  const float* x0  = (const float*)d_in[0];
  const int*   ei  = (const int*)d_in[1];
  const float* eps = (const float*)d_in[2];
  const float* W1  = (const float*)d_in[3];
  const float* b1  = (const float*)d_in[4];
  const float* g1  = (const float*)d_in[5];
  const float* be1 = (const float*)d_in[6];
  const float* W2  = (const float*)d_in[7];
  const float* b2  = (const float*)d_in[8];
  const float* g2  = (const float*)d_in[9];
  const float* be2 = (const float*)d_in[10];
  const float* bng = (const float*)d_in[11];
  const float* bnb = (const float*)d_in[12];
  const int* src = ei;
  const int* dst = ei + N_EDGES;
  float* OUT = (float*)d_out;

  char* p = (char*)d_ws;
  auto carve = [&](size_t bytes)->char*{ char* r = p; p += (bytes + 255) & ~(size_t)255; return r; };
  int*   offs    = (int*)carve((size_t)N_NODES*sizeof(int));
  int*   offe    = (int*)carve((size_t)N_NODES*sizeof(int));
  int*   btail   = (int*)carve(NBUCKC*sizeof(int));
  int*   pairs   = (int*)carve((size_t)NBUCKC*SLABC*sizeof(int));        // 7.2 MB
  int*   srclist = (int*)carve((size_t)NBUCKC*SLABC*sizeof(int));        // 7.2 MB
  unsigned short* XB0 = (unsigned short*)carve((size_t)N_NODES*CH*2);    // 12.8 MB fp16
  unsigned short* XB1 = (unsigned short*)carve((size_t)N_NODES*CH*2);    // 12.8 MB fp16
  _Float16* Wt   = (_Float16*)carve((size_t)NLAYERS*2*4096*2);
  float* bfb     = (float*)carve((size_t)NLAYERS*2*64*sizeof(float));
  float* ogb     = (float*)carve((size_t)2*NLAYERS*64*sizeof(float));

  const int npart = (N_EDGES + EPB - 1)/EPB;   // 196
  binit_kernel<<<1, 256, 0, stream>>>(btail);
  part_kernel<<<npart, 256, 0, stream>>>(src, dst, btail, pairs);
  csr_kernel<<<NBUCKC*8, 256, 0, stream>>>(pairs, btail, offs, offe, srclist);
  prep_kernel<<<48, 256, 0, stream>>>(W1,b1,g1,be1,W2,b2,g2,be2,bng,bnb,Wt,bfb,ogb);
  xcvt_kernel<<<(N_NODES*CH/8 + 255)/256, 256, 0, stream>>>(x0, XB0);

  const int nlb = (N_NODES + 63)/64;   // 1563
  // Ping-pong fp16 features: l0 XB0->XB1, l1 XB1->XB0, l2 XB0->OUT (fp32)
  layer_kernel<<<nlb, 256, 0, stream>>>(XB0, offs, offe, srclist, eps, Wt, bfb, ogb, 0, OUT, (_Float16*)XB1, 1);
  layer_kernel<<<nlb, 256, 0, stream>>>(XB1, offs, offe, srclist, eps, Wt, bfb, ogb, 1, OUT, (_Float16*)XB0, 1);
  layer_kernel<<<nlb, 256, 0, stream>>>(XB0, offs, offe, srclist, eps, Wt, bfb, ogb, 2, OUT, (_Float16*)XB1, 0);
}

// Round 9
// 306.870 us; speedup vs baseline: 6.6313x; 1.0499x over previous
//
#include <hip/hip_runtime.h>
#include <hip/hip_fp16.h>

#define N_NODES 100000
#define N_EDGES 1600000
#define CH 64
#define NLAYERS 3
#define NBUCKC 98          // coarse buckets of 1024 dst nodes
#define SLABC 18432        // coarse slab capacity (mean 16327, sd 127 -> +16 sigma)
#define NFINE (NBUCKC*8)   // 784 fine buckets of 128 dst nodes
#define SLABF 2560         // fine slab capacity (mean 2048, sd 45 -> +11 sigma)
#define EPB 8192           // edges per part1 block (196 blocks)

typedef _Float16 half8 __attribute__((ext_vector_type(8)));
typedef float floatx4 __attribute__((ext_vector_type(4)));

static __device__ __forceinline__ float4 ld4(const float* p){ return *(const float4*)p; }
static __device__ __forceinline__ unsigned pack2(float a, float b){
  __half2 h = __float22half2_rn(make_float2(a, b));
  return *(unsigned*)&h;
}
static __device__ __forceinline__ float2 up2(unsigned u){
  __half2 h = *(__half2*)&u;
  return __half22float2(h);
}

// ---- tail init: coarse + fine slab cursors ----
__global__ __launch_bounds__(256) void binit_kernel(int* __restrict__ btail, int* __restrict__ ftail){
  int i = blockIdx.x*256 + threadIdx.x;
  if (i < NBUCKC) btail[i] = i*SLABC;
  if (i < NFINE)  ftail[i] = i*SLABF;
}

// ---- part1: edges -> 98 coarse slabs; packed = src | ((dst&1023)<<20) ----
__global__ __launch_bounds__(256) void part1_kernel(const int* __restrict__ src, const int* __restrict__ dst,
                                                    int* __restrict__ btail, int* __restrict__ pairs){
  __shared__ int lpos[NBUCKC];
  __shared__ int gb[NBUCKC];
  int tid = threadIdx.x;
  if (tid < NBUCKC) lpos[tid] = 0;
  __syncthreads();
  int base = blockIdx.x * EPB;
  #pragma unroll 4
  for (int k = 0; k < EPB/256; ++k) {
    int e = base + k*256 + tid;
    if (e < N_EDGES) atomicAdd(&lpos[dst[e] >> 10], 1);
  }
  __syncthreads();
  if (tid < NBUCKC) {
    int cc = lpos[tid];
    gb[tid] = cc ? atomicAdd(&btail[tid], cc) : 0;
    lpos[tid] = 0;
  }
  __syncthreads();
  #pragma unroll 4
  for (int k = 0; k < EPB/256; ++k) {
    int e = base + k*256 + tid;
    if (e < N_EDGES) {
      int d = dst[e];
      int bk = d >> 10;
      int p = atomicAdd(&lpos[bk], 1);
      int idx = gb[bk] + p;
      if (idx < (bk+1)*SLABC)                   // memory-safety clamp (statistically never)
        pairs[idx] = src[e] | ((d & 1023) << 20);
    }
  }
}

// ---- part2: split each coarse slab into 8 fine sub-slabs (784 blocks, 1/8 edge-segment each) ----
// Two passes over the segment (2nd L2-hot): banked count -> global reserve -> ballot-aggregated place.
__global__ __launch_bounds__(256) void part2_kernel(const int* __restrict__ pairs, const int* __restrict__ btail,
                                                    int* __restrict__ ftail, int* __restrict__ pairs2){
  __shared__ int cnt[8*32];
  __shared__ int scur[8];
  int tid = threadIdx.x;
  int b = blockIdx.x >> 3;        // coarse bucket
  int sg = blockIdx.x & 7;        // segment of the slab's edge range
  int e0 = b*SLABC;
  int e1 = btail[b]; int emax = e0 + SLABC; if (e1 > emax) e1 = emax;
  int len = e1 - e0;
  int s0 = e0 + (int)(((long)len * sg) >> 3);
  int s1 = e0 + (int)(((long)len * (sg+1)) >> 3);
  if (tid < 256) { cnt[tid & 255] = 0; }
  __syncthreads();
  // pass 1: banked count of fine sub-bucket = dl>>7
  for (int i = s0 + tid; i < s1; i += 256) {
    int p = pairs[i];
    int fk = ((unsigned)p >> 27);     // (dl>>7): dl = bits 20..29
    atomicAdd(&cnt[(fk<<5) + (tid & 31)], 1);
  }
  __syncthreads();
  if (tid < 8) {
    int tot = 0;
    #pragma unroll
    for (int r = 0; r < 32; ++r) tot += cnt[(tid<<5) + r];
    scur[tid] = tot ? atomicAdd(&ftail[(b<<3) + tid], tot) : 0;
  }
  __syncthreads();
  // pass 2: place via wave-ballot aggregation (one LDS atomic per wave-batch per bucket)
  int lane = tid & 63;
  int wbase = s0 + (tid >> 6)*64;
  for (int i = wbase; i < s1; i += 256) {
    int idx = i + lane - (tid >> 6)*64 + (tid >> 6)*64;  // = i + 0 ... keep simple below
    int e = i + lane - lane + lane;                       // e == i + lane offset handled directly:
    (void)idx; (void)e;
    int ei = i + lane - lane;                             // base of this wave batch
    int my = ei + lane;
    bool valid = (my < s1);
    int p = valid ? pairs[my] : 0;
    int fk = valid ? (int)((unsigned)p >> 27) : -1;
    #pragma unroll
    for (int j = 0; j < 8; ++j) {
      unsigned long long mask = __ballot(valid && fk == j);
      if (mask) {
        int leader = __ffsll((long long)mask) - 1;
        int cc = __popcll(mask);
        int basep = 0;
        if (lane == leader) basep = atomicAdd(&scur[j], cc);
        basep = __shfl(basep, leader, 64);
        if (valid && fk == j) {
          int rank = __popcll(mask & ((1ull << lane) - 1ull));
          int pos = basep + rank;
          if (pos < ((b<<3) + j + 1)*SLABF)     // memory-safety clamp
            pairs2[pos] = p;
        }
      }
    }
  }
}

// ---- csr: per fine sub-slab (784 blocks): hist 128 nodes, scan, scatter ----
__global__ __launch_bounds__(256) void csr_kernel(const int* __restrict__ pairs2, const int* __restrict__ ftail,
                                                  int* __restrict__ offs, int* __restrict__ offe,
                                                  int* __restrict__ srclist){
  __shared__ int c[128];
  __shared__ int s[128];
  __shared__ int cur[128];
  int t = threadIdx.x;
  int f = blockIdx.x;
  int e0 = f*SLABF;
  int e1 = ftail[f]; int emax = e0 + SLABF; if (e1 > emax) e1 = emax;
  if (t < 128) c[t] = 0;
  __syncthreads();
  for (int i = e0 + t; i < e1; i += 256) {
    int p = pairs2[i];
    atomicAdd(&c[((unsigned)p >> 20) & 127], 1);
  }
  __syncthreads();
  int v = (t < 128) ? c[t] : 0;
  if (t < 128) s[t] = v;
  __syncthreads();
  #pragma unroll
  for (int o = 1; o < 128; o <<= 1){
    int u = 0;
    if (t < 128 && t >= o) u = s[t-o];
    __syncthreads();
    if (t < 128) s[t] += u;
    __syncthreads();
  }
  if (t < 128) {
    int excl = s[t] - v;
    cur[t] = excl;
    int n = (f >> 3)*1024 + (f & 7)*128 + t;
    if (n < N_NODES) { offs[n] = e0 + excl; offe[n] = e0 + excl + v; }
  }
  __syncthreads();
  for (int i = e0 + t; i < e1; i += 256) {
    int p = pairs2[i];
    int pos = atomicAdd(&cur[((unsigned)p >> 20) & 127], 1);
    if (pos < SLABF)                            // memory-safety clamp
      srclist[e0 + pos] = p & 0xFFFFF;
  }
}

// ---- fold BN into weights (fp16, transposed, XOR-swizzled) and biases (fp32) ----
__global__ __launch_bounds__(256) void prep_kernel(
    const float* __restrict__ W1, const float* __restrict__ b1,
    const float* __restrict__ g1, const float* __restrict__ be1,
    const float* __restrict__ W2, const float* __restrict__ b2,
    const float* __restrict__ g2, const float* __restrict__ be2,
    const float* __restrict__ bng, const float* __restrict__ bnb,
    _Float16* __restrict__ Wt, float* __restrict__ bf, float* __restrict__ ogb){
  const float s = 0.9999950000374997f;   // 1/sqrt(1+1e-5)
  int i = blockIdx.x*256 + threadIdx.x;
  if (i < NLAYERS*4096) {
    int l = i >> 12, rem = i & 4095, k = rem >> 6, n = rem & 63;
    int di = n*64 + (((k>>3) ^ (n&7))<<3) + (k&7);
    Wt[l*8192 + di]        = (_Float16)(W1[i] * g1[l*64+n] * s);
    Wt[l*8192 + 4096 + di] = (_Float16)(W2[i] * g2[l*64+n] * s);
  }
  if (i < NLAYERS*64) {
    int l = i >> 6, j = i & 63;
    bf[l*128 + j]      = b1[i]*g1[i]*s + be1[i];
    bf[l*128 + 64 + j] = b2[i]*g2[i]*s + be2[i];
    ogb[i]                 = bng[i]*s;
    ogb[NLAYERS*64 + i]    = bnb[i];
  }
}

// ---- x0 (fp32) -> XB0 (fp16) ----
__global__ __launch_bounds__(256) void xcvt_kernel(const float* __restrict__ x, unsigned short* __restrict__ xb){
  int i = (blockIdx.x*256 + threadIdx.x)*8;
  if (i < N_NODES*CH) {
    float4 v0 = ld4(x + i), v1 = ld4(x + i + 4);
    uint4 w;
    w.x = pack2(v0.x, v0.y); w.y = pack2(v0.z, v0.w);
    w.z = pack2(v1.x, v1.y); w.w = pack2(v1.z, v1.w);
    *(uint4*)(xb + i) = w;
  }
}

// ---- fused layer: gather-agg straight into LDS H (no atomics) -> MFMA MLP -> epilogue ----
__global__ __launch_bounds__(256) void layer_kernel(const unsigned short* __restrict__ XBin,
                                                    const int* __restrict__ offs, const int* __restrict__ offe,
                                                    const int* __restrict__ srclist,
                                                    const float* __restrict__ eps,
                                                    const _Float16* __restrict__ Wt,
                                                    const float* __restrict__ bf, const float* __restrict__ ogb,
                                                    int layer, float* __restrict__ outf,
                                                    _Float16* __restrict__ outb, int relu_out){
  __shared__ _Float16 HsA[64*64];
  __shared__ _Float16 Wts[64*64];
  int tid = threadIdx.x;
  int b = blockIdx.x;
  const _Float16* Wg = Wt + layer*8192;
  *(uint4*)&Wts[tid*8]       = *(const uint4*)&Wg[tid*8];
  *(uint4*)&Wts[(tid+256)*8] = *(const uint4*)&Wg[(tid+256)*8];

  float ep = 1.0f + eps[layer];
  int kb = tid & 7;
  const unsigned short* xr = XBin + (kb << 3);
  #pragma unroll
  for (int p = 0; p < 2; ++p) {
    int nl = p*32 + (tid >> 3);
    int n = b*64 + nl;
    float A[8] = {0,0,0,0,0,0,0,0};
    float B[8] = {0,0,0,0,0,0,0,0};
    float C[8] = {0,0,0,0,0,0,0,0};
    float D[8] = {0,0,0,0,0,0,0,0};
    float r[8] = {0,0,0,0,0,0,0,0};
    if (n < N_NODES) {
      #define ADD8(acc, u) { float2 f; \
        f = up2((u).x); acc[0] += f.x; acc[1] += f.y; \
        f = up2((u).y); acc[2] += f.x; acc[3] += f.y; \
        f = up2((u).z); acc[4] += f.x; acc[5] += f.y; \
        f = up2((u).w); acc[6] += f.x; acc[7] += f.y; }
      int e0 = offs[n], e1 = offe[n];
      int e = e0;
      for (; e+4 <= e1; e += 4) {
        int s0 = srclist[e], s1 = srclist[e+1], s2 = srclist[e+2], s3 = srclist[e+3];
        uint4 u0 = *(const uint4*)(xr + (size_t)s0*CH);
        uint4 u1 = *(const uint4*)(xr + (size_t)s1*CH);
        uint4 u2 = *(const uint4*)(xr + (size_t)s2*CH);
        uint4 u3 = *(const uint4*)(xr + (size_t)s3*CH);
        ADD8(A, u0) ADD8(B, u1) ADD8(C, u2) ADD8(D, u3)
      }
      for (; e < e1; ++e) {
        int s0 = srclist[e];
        uint4 u0 = *(const uint4*)(xr + (size_t)s0*CH);
        ADD8(A, u0)
      }
      #undef ADD8
      uint4 sv = *(const uint4*)(xr + (size_t)n*CH);
      float sf[8];
      { float2 f;
        f = up2(sv.x); sf[0]=f.x; sf[1]=f.y;
        f = up2(sv.y); sf[2]=f.x; sf[3]=f.y;
        f = up2(sv.z); sf[4]=f.x; sf[5]=f.y;
        f = up2(sv.w); sf[6]=f.x; sf[7]=f.y; }
      #pragma unroll
      for (int i = 0; i < 8; ++i) r[i] = fmaf(ep, sf[i], (A[i] + B[i]) + (C[i] + D[i]));
    }
    uint4 w;
    w.x = pack2(r[0], r[1]); w.y = pack2(r[2], r[3]);
    w.z = pack2(r[4], r[5]); w.w = pack2(r[6], r[7]);
    *(uint4*)&HsA[nl*64 + ((kb ^ (nl&7))<<3)] = w;
  }
  __syncthreads();

  int lane = tid & 63;
  int wid = tid >> 6;
  int c = lane & 15;
  int q = lane >> 4;
  int mbase = wid*16;
  int ma = mbase + c;

  half8 a0 = *(const half8*)&HsA[ma*64 + (((q)   ^ (ma&7))<<3)];
  half8 a1 = *(const half8*)&HsA[ma*64 + (((4+q) ^ (ma&7))<<3)];

  floatx4 acc[4];
  #pragma unroll
  for (int nt = 0; nt < 4; ++nt) {
    int n = nt*16 + c;
    float bv = bf[layer*128 + n];
    floatx4 Acc = {bv, bv, bv, bv};
    half8 b0 = *(const half8*)&Wts[n*64 + (((q)   ^ (n&7))<<3)];
    half8 b1 = *(const half8*)&Wts[n*64 + (((4+q) ^ (n&7))<<3)];
    Acc = __builtin_amdgcn_mfma_f32_16x16x32_f16(a0, b0, Acc, 0, 0, 0);
    Acc = __builtin_amdgcn_mfma_f32_16x16x32_f16(a1, b1, Acc, 0, 0, 0);
    acc[nt] = Acc;
  }
  __syncthreads();

  #pragma unroll
  for (int nt = 0; nt < 4; ++nt) {
    int n = nt*16 + c;
    #pragma unroll
    for (int r = 0; r < 4; ++r) {
      int m = mbase + q*4 + r;
      float h = acc[nt][r]; h = h > 0.f ? h : 0.f;
      HsA[m*64 + (((n>>3) ^ (m&7))<<3) + (n&7)] = (_Float16)h;
    }
  }
  *(uint4*)&Wts[tid*8]       = *(const uint4*)&Wg[4096 + tid*8];
  *(uint4*)&Wts[(tid+256)*8] = *(const uint4*)&Wg[4096 + (tid+256)*8];
  __syncthreads();

  half8 c0 = *(const half8*)&HsA[ma*64 + (((q)   ^ (ma&7))<<3)];
  half8 c1 = *(const half8*)&HsA[ma*64 + (((4+q) ^ (ma&7))<<3)];
  floatx4 acc2[4];
  #pragma unroll
  for (int nt = 0; nt < 4; ++nt) {
    int n = nt*16 + c;
    float bv = bf[layer*128 + 64 + n];
    floatx4 Acc = {bv, bv, bv, bv};
    half8 b0 = *(const half8*)&Wts[n*64 + (((q)   ^ (n&7))<<3)];
    half8 b1 = *(const half8*)&Wts[n*64 + (((4+q) ^ (n&7))<<3)];
    Acc = __builtin_amdgcn_mfma_f32_16x16x32_f16(c0, b0, Acc, 0, 0, 0);
    Acc = __builtin_amdgcn_mfma_f32_16x16x32_f16(c1, b1, Acc, 0, 0, 0);
    acc2[nt] = Acc;
  }

  #pragma unroll
  for (int nt = 0; nt < 4; ++nt) {
    int n = nt*16 + c;
    float og = ogb[layer*64 + n];
    float ob = ogb[NLAYERS*64 + layer*64 + n];
    #pragma unroll
    for (int r = 0; r < 4; ++r) {
      int m = mbase + q*4 + r;
      int gnode = b*64 + m;
      if (gnode < N_NODES) {
        float h = acc2[nt][r]; h = h > 0.f ? h : 0.f;
        float o = fmaf(og, h, ob);
        if (relu_out) {
          o = o > 0.f ? o : 0.f;
          outb[(size_t)gnode*CH + n] = (_Float16)o;
        } else {
          outf[(size_t)gnode*CH + n] = o;
        }
      }
    }
  }
}

extern "C" void kernel_launch(void* const* d_in, const int* in_sizes, int n_in,
                              void* d_out, int out_size, void* d_ws, size_t ws_size,
                              hipStream_t stream) {
  const float* x0  = (const float*)d_in[0];
  const int*   ei  = (const int*)d_in[1];
  const float* eps = (const float*)d_in[2];
  const float* W1  = (const float*)d_in[3];
  const float* b1  = (const float*)d_in[4];
  const float* g1  = (const float*)d_in[5];
  const float* be1 = (const float*)d_in[6];
  const float* W2  = (const float*)d_in[7];
  const float* b2  = (const float*)d_in[8];
  const float* g2  = (const float*)d_in[9];
  const float* be2 = (const float*)d_in[10];
  const float* bng = (const float*)d_in[11];
  const float* bnb = (const float*)d_in[12];
  const int* src = ei;
  const int* dst = ei + N_EDGES;
  float* OUT = (float*)d_out;

  char* p = (char*)d_ws;
  auto carve = [&](size_t bytes)->char*{ char* r = p; p += (bytes + 255) & ~(size_t)255; return r; };
  int*   offs    = (int*)carve((size_t)N_NODES*sizeof(int));
  int*   offe    = (int*)carve((size_t)N_NODES*sizeof(int));
  int*   btail   = (int*)carve(NBUCKC*sizeof(int));
  int*   ftail   = (int*)carve(NFINE*sizeof(int));
  int*   pairs   = (int*)carve((size_t)NBUCKC*SLABC*sizeof(int));        // 7.2 MB
  int*   pairs2  = (int*)carve((size_t)NFINE*SLABF*sizeof(int));         // 8.0 MB
  int*   srclist = (int*)carve((size_t)NFINE*SLABF*sizeof(int));         // 8.0 MB
  unsigned short* XB0 = (unsigned short*)carve((size_t)N_NODES*CH*2);    // 12.8 MB fp16
  unsigned short* XB1 = (unsigned short*)carve((size_t)N_NODES*CH*2);    // 12.8 MB fp16
  _Float16* Wt   = (_Float16*)carve((size_t)NLAYERS*2*4096*2);
  float* bfb     = (float*)carve((size_t)NLAYERS*2*64*sizeof(float));
  float* ogb     = (float*)carve((size_t)2*NLAYERS*64*sizeof(float));

  const int npart = (N_EDGES + EPB - 1)/EPB;   // 196
  binit_kernel<<<(NFINE+255)/256, 256, 0, stream>>>(btail, ftail);
  part1_kernel<<<npart, 256, 0, stream>>>(src, dst, btail, pairs);
  part2_kernel<<<NFINE, 256, 0, stream>>>(pairs, btail, ftail, pairs2);
  csr_kernel<<<NFINE, 256, 0, stream>>>(pairs2, ftail, offs, offe, srclist);
  prep_kernel<<<48, 256, 0, stream>>>(W1,b1,g1,be1,W2,b2,g2,be2,bng,bnb,Wt,bfb,ogb);
  xcvt_kernel<<<(N_NODES*CH/8 + 255)/256, 256, 0, stream>>>(x0, XB0);

  const int nlb = (N_NODES + 63)/64;   // 1563
  layer_kernel<<<nlb, 256, 0, stream>>>(XB0, offs, offe, srclist, eps, Wt, bfb, ogb, 0, OUT, (_Float16*)XB1, 1);
  layer_kernel<<<nlb, 256, 0, stream>>>(XB1, offs, offe, srclist, eps, Wt, bfb, ogb, 1, OUT, (_Float16*)XB0, 1);
  layer_kernel<<<nlb, 256, 0, stream>>>(XB0, offs, offe, srclist, eps, Wt, bfb, ogb, 2, OUT, (_Float16*)XB1, 0);
}

// Round 10
// 291.470 us; speedup vs baseline: 6.9817x; 1.0528x over previous
//
#include <hip/hip_runtime.h>
#include <hip/hip_fp16.h>

#define N_NODES 100000
#define N_EDGES 1600000
#define CH 64
#define NLAYERS 3
#define NBUCKC 98          // coarse buckets of 1024 dst nodes
#define SLABC 18432        // coarse slab capacity (mean 16327, sd 127 -> +16 sigma)
#define NFINE (NBUCKC*8)   // 784 fine buckets of 128 dst nodes
#define SLABF 2560         // fine slab capacity (mean 2048, sd 45 -> +11 sigma)
#define EPB 8192           // edges per part1 block (196 blocks)

typedef _Float16 half8 __attribute__((ext_vector_type(8)));
typedef float floatx4 __attribute__((ext_vector_type(4)));

static __device__ __forceinline__ float4 ld4(const float* p){ return *(const float4*)p; }
static __device__ __forceinline__ unsigned pack2(float a, float b){
  __half2 h = __float22half2_rn(make_float2(a, b));
  return *(unsigned*)&h;
}
static __device__ __forceinline__ float2 up2(unsigned u){
  __half2 h = *(__half2*)&u;
  return __half22float2(h);
}
static __device__ __forceinline__ half8 ldh8(const unsigned short* p){
  uint4 u = *(const uint4*)p;
  return *(half8*)&u;
}

// ---- tail init: coarse + fine slab cursors ----
__global__ __launch_bounds__(256) void binit_kernel(int* __restrict__ btail, int* __restrict__ ftail){
  int i = blockIdx.x*256 + threadIdx.x;
  if (i < NBUCKC) btail[i] = i*SLABC;
  if (i < NFINE)  ftail[i] = i*SLABF;
}

// ---- part1: edges -> 98 coarse slabs; packed = src | ((dst&1023)<<20) ----
__global__ __launch_bounds__(256) void part1_kernel(const int* __restrict__ src, const int* __restrict__ dst,
                                                    int* __restrict__ btail, int* __restrict__ pairs){
  __shared__ int lpos[NBUCKC];
  __shared__ int gb[NBUCKC];
  int tid = threadIdx.x;
  if (tid < NBUCKC) lpos[tid] = 0;
  __syncthreads();
  int base = blockIdx.x * EPB;
  #pragma unroll 4
  for (int k = 0; k < EPB/256; ++k) {
    int e = base + k*256 + tid;
    if (e < N_EDGES) atomicAdd(&lpos[dst[e] >> 10], 1);
  }
  __syncthreads();
  if (tid < NBUCKC) {
    int cc = lpos[tid];
    gb[tid] = cc ? atomicAdd(&btail[tid], cc) : 0;
    lpos[tid] = 0;
  }
  __syncthreads();
  #pragma unroll 4
  for (int k = 0; k < EPB/256; ++k) {
    int e = base + k*256 + tid;
    if (e < N_EDGES) {
      int d = dst[e];
      int bk = d >> 10;
      int p = atomicAdd(&lpos[bk], 1);
      int idx = gb[bk] + p;
      if (idx < (bk+1)*SLABC)                   // memory-safety clamp (statistically never)
        pairs[idx] = src[e] | ((d & 1023) << 20);
    }
  }
}

// ---- part2: split each coarse slab into 8 fine sub-slabs (784 blocks, 1/8 edge-segment each) ----
__global__ __launch_bounds__(256) void part2_kernel(const int* __restrict__ pairs, const int* __restrict__ btail,
                                                    int* __restrict__ ftail, int* __restrict__ pairs2){
  __shared__ int cnt[8*32];
  __shared__ int scur[8];
  int tid = threadIdx.x;
  int b = blockIdx.x >> 3;        // coarse bucket
  int sg = blockIdx.x & 7;        // segment of the slab's edge range
  int e0 = b*SLABC;
  int e1 = btail[b]; int emax = e0 + SLABC; if (e1 > emax) e1 = emax;
  int len = e1 - e0;
  int s0 = e0 + (int)(((long)len * sg) >> 3);
  int s1 = e0 + (int)(((long)len * (sg+1)) >> 3);
  cnt[tid] = 0;
  __syncthreads();
  for (int i = s0 + tid; i < s1; i += 256) {
    int p = pairs[i];
    int fk = ((unsigned)p >> 27);
    atomicAdd(&cnt[(fk<<5) + (tid & 31)], 1);
  }
  __syncthreads();
  if (tid < 8) {
    int tot = 0;
    #pragma unroll
    for (int r = 0; r < 32; ++r) tot += cnt[(tid<<5) + r];
    scur[tid] = tot ? atomicAdd(&ftail[(b<<3) + tid], tot) : 0;
  }
  __syncthreads();
  int lane = tid & 63;
  for (int i = s0 + (tid >> 6)*64; i < s1; i += 256) {
    int my = i + lane;
    bool valid = (my < s1);
    int p = valid ? pairs[my] : 0;
    int fk = valid ? (int)((unsigned)p >> 27) : -1;
    #pragma unroll
    for (int j = 0; j < 8; ++j) {
      unsigned long long mask = __ballot(valid && fk == j);
      if (mask) {
        int leader = __ffsll((long long)mask) - 1;
        int cc = __popcll(mask);
        int basep = 0;
        if (lane == leader) basep = atomicAdd(&scur[j], cc);
        basep = __shfl(basep, leader, 64);
        if (valid && fk == j) {
          int rank = __popcll(mask & ((1ull << lane) - 1ull));
          int pos = basep + rank;
          if (pos < ((b<<3) + j + 1)*SLABF)     // memory-safety clamp
            pairs2[pos] = p;
        }
      }
    }
  }
}

// ---- csr: per fine sub-slab (784 blocks): hist 128 nodes, scan, scatter ----
__global__ __launch_bounds__(256) void csr_kernel(const int* __restrict__ pairs2, const int* __restrict__ ftail,
                                                  int* __restrict__ offs, int* __restrict__ offe,
                                                  int* __restrict__ srclist){
  __shared__ int c[128];
  __shared__ int s[128];
  __shared__ int cur[128];
  int t = threadIdx.x;
  int f = blockIdx.x;
  int e0 = f*SLABF;
  int e1 = ftail[f]; int emax = e0 + SLABF; if (e1 > emax) e1 = emax;
  if (t < 128) c[t] = 0;
  __syncthreads();
  for (int i = e0 + t; i < e1; i += 256) {
    int p = pairs2[i];
    atomicAdd(&c[((unsigned)p >> 20) & 127], 1);
  }
  __syncthreads();
  int v = (t < 128) ? c[t] : 0;
  if (t < 128) s[t] = v;
  __syncthreads();
  #pragma unroll
  for (int o = 1; o < 128; o <<= 1){
    int u = 0;
    if (t < 128 && t >= o) u = s[t-o];
    __syncthreads();
    if (t < 128) s[t] += u;
    __syncthreads();
  }
  if (t < 128) {
    int excl = s[t] - v;
    cur[t] = excl;
    int n = (f >> 3)*1024 + (f & 7)*128 + t;
    if (n < N_NODES) { offs[n] = e0 + excl; offe[n] = e0 + excl + v; }
  }
  __syncthreads();
  for (int i = e0 + t; i < e1; i += 256) {
    int p = pairs2[i];
    int pos = atomicAdd(&cur[((unsigned)p >> 20) & 127], 1);
    if (pos < SLABF)                            // memory-safety clamp
      srclist[e0 + pos] = p & 0xFFFFF;
  }
}

// ---- fold BN into weights (fp16, transposed, XOR-swizzled) and biases (fp32) ----
__global__ __launch_bounds__(256) void prep_kernel(
    const float* __restrict__ W1, const float* __restrict__ b1,
    const float* __restrict__ g1, const float* __restrict__ be1,
    const float* __restrict__ W2, const float* __restrict__ b2,
    const float* __restrict__ g2, const float* __restrict__ be2,
    const float* __restrict__ bng, const float* __restrict__ bnb,
    _Float16* __restrict__ Wt, float* __restrict__ bf, float* __restrict__ ogb){
  const float s = 0.9999950000374997f;   // 1/sqrt(1+1e-5)
  int i = blockIdx.x*256 + threadIdx.x;
  if (i < NLAYERS*4096) {
    int l = i >> 12, rem = i & 4095, k = rem >> 6, n = rem & 63;
    int di = n*64 + (((k>>3) ^ (n&7))<<3) + (k&7);
    Wt[l*8192 + di]        = (_Float16)(W1[i] * g1[l*64+n] * s);
    Wt[l*8192 + 4096 + di] = (_Float16)(W2[i] * g2[l*64+n] * s);
  }
  if (i < NLAYERS*64) {
    int l = i >> 6, j = i & 63;
    bf[l*128 + j]      = b1[i]*g1[i]*s + be1[i];
    bf[l*128 + 64 + j] = b2[i]*g2[i]*s + be2[i];
    ogb[i]                 = bng[i]*s;
    ogb[NLAYERS*64 + i]    = bnb[i];
  }
}

// ---- x0 (fp32) -> XB0 (fp16) ----
__global__ __launch_bounds__(256) void xcvt_kernel(const float* __restrict__ x, unsigned short* __restrict__ xb){
  int i = (blockIdx.x*256 + threadIdx.x)*8;
  if (i < N_NODES*CH) {
    float4 v0 = ld4(x + i), v1 = ld4(x + i + 4);
    uint4 w;
    w.x = pack2(v0.x, v0.y); w.y = pack2(v0.z, v0.w);
    w.z = pack2(v1.x, v1.y); w.w = pack2(v1.z, v1.w);
    *(uint4*)(xb + i) = w;
  }
}

// ---- fused layer: gather (8 chains, packed-f16 accum) -> MFMA MLP -> epilogue ----
__global__ __launch_bounds__(256) void layer_kernel(const unsigned short* __restrict__ XBin,
                                                    const int* __restrict__ offs, const int* __restrict__ offe,
                                                    const int* __restrict__ srclist,
                                                    const float* __restrict__ eps,
                                                    const _Float16* __restrict__ Wt,
                                                    const float* __restrict__ bf, const float* __restrict__ ogb,
                                                    int layer, float* __restrict__ outf,
                                                    _Float16* __restrict__ outb, int relu_out){
  __shared__ _Float16 HsA[64*64];
  __shared__ _Float16 Wts[64*64];
  int tid = threadIdx.x;
  int b = blockIdx.x;
  const _Float16* Wg = Wt + layer*8192;
  *(uint4*)&Wts[tid*8]       = *(const uint4*)&Wg[tid*8];
  *(uint4*)&Wts[(tid+256)*8] = *(const uint4*)&Wg[(tid+256)*8];

  float ep = 1.0f + eps[layer];
  int kb = tid & 7;
  const unsigned short* xr = XBin + (kb << 3);
  #pragma unroll
  for (int p = 0; p < 2; ++p) {
    int nl = p*32 + (tid >> 3);
    int n = b*64 + nl;
    float r[8] = {0,0,0,0,0,0,0,0};
    if (n < N_NODES) {
      half8 A = (half8)(_Float16)0, B = A, C = A, D = A, E = A, F = A, G = A, H = A;
      int e0 = offs[n], e1 = offe[n];
      int e = e0;
      for (; e+8 <= e1; e += 8) {            // 8 independent chains, 8 loads in flight
        int s0 = srclist[e],   s1 = srclist[e+1], s2 = srclist[e+2], s3 = srclist[e+3];
        int s4 = srclist[e+4], s5 = srclist[e+5], s6 = srclist[e+6], s7 = srclist[e+7];
        half8 u0 = ldh8(xr + (size_t)s0*CH);
        half8 u1 = ldh8(xr + (size_t)s1*CH);
        half8 u2 = ldh8(xr + (size_t)s2*CH);
        half8 u3 = ldh8(xr + (size_t)s3*CH);
        half8 u4 = ldh8(xr + (size_t)s4*CH);
        half8 u5 = ldh8(xr + (size_t)s5*CH);
        half8 u6 = ldh8(xr + (size_t)s6*CH);
        half8 u7 = ldh8(xr + (size_t)s7*CH);
        A += u0; B += u1; C += u2; D += u3; E += u4; F += u5; G += u6; H += u7;
      }
      for (; e+4 <= e1; e += 4) {
        int s0 = srclist[e], s1 = srclist[e+1], s2 = srclist[e+2], s3 = srclist[e+3];
        half8 u0 = ldh8(xr + (size_t)s0*CH);
        half8 u1 = ldh8(xr + (size_t)s1*CH);
        half8 u2 = ldh8(xr + (size_t)s2*CH);
        half8 u3 = ldh8(xr + (size_t)s3*CH);
        A += u0; B += u1; C += u2; D += u3;
      }
      for (; e < e1; ++e) {
        A += ldh8(xr + (size_t)srclist[e]*CH);
      }
      half8 S = ((A + B) + (C + D)) + ((E + F) + (G + H));
      half8 sv = ldh8(xr + (size_t)n*CH);
      #pragma unroll
      for (int i = 0; i < 8; ++i) r[i] = fmaf(ep, (float)sv[i], (float)S[i]);
    }
    uint4 w;
    w.x = pack2(r[0], r[1]); w.y = pack2(r[2], r[3]);
    w.z = pack2(r[4], r[5]); w.w = pack2(r[6], r[7]);
    *(uint4*)&HsA[nl*64 + ((kb ^ (nl&7))<<3)] = w;
  }
  __syncthreads();

  int lane = tid & 63;
  int wid = tid >> 6;
  int c = lane & 15;
  int q = lane >> 4;
  int mbase = wid*16;
  int ma = mbase + c;

  half8 a0 = *(const half8*)&HsA[ma*64 + (((q)   ^ (ma&7))<<3)];
  half8 a1 = *(const half8*)&HsA[ma*64 + (((4+q) ^ (ma&7))<<3)];

  floatx4 acc[4];
  #pragma unroll
  for (int nt = 0; nt < 4; ++nt) {
    int n = nt*16 + c;
    float bv = bf[layer*128 + n];
    floatx4 Acc = {bv, bv, bv, bv};
    half8 b0 = *(const half8*)&Wts[n*64 + (((q)   ^ (n&7))<<3)];
    half8 b1 = *(const half8*)&Wts[n*64 + (((4+q) ^ (n&7))<<3)];
    Acc = __builtin_amdgcn_mfma_f32_16x16x32_f16(a0, b0, Acc, 0, 0, 0);
    Acc = __builtin_amdgcn_mfma_f32_16x16x32_f16(a1, b1, Acc, 0, 0, 0);
    acc[nt] = Acc;
  }
  __syncthreads();

  #pragma unroll
  for (int nt = 0; nt < 4; ++nt) {
    int n = nt*16 + c;
    #pragma unroll
    for (int r = 0; r < 4; ++r) {
      int m = mbase + q*4 + r;
      float h = acc[nt][r]; h = h > 0.f ? h : 0.f;
      HsA[m*64 + (((n>>3) ^ (m&7))<<3) + (n&7)] = (_Float16)h;
    }
  }
  *(uint4*)&Wts[tid*8]       = *(const uint4*)&Wg[4096 + tid*8];
  *(uint4*)&Wts[(tid+256)*8] = *(const uint4*)&Wg[4096 + (tid+256)*8];
  __syncthreads();

  half8 c0 = *(const half8*)&HsA[ma*64 + (((q)   ^ (ma&7))<<3)];
  half8 c1 = *(const half8*)&HsA[ma*64 + (((4+q) ^ (ma&7))<<3)];
  floatx4 acc2[4];
  #pragma unroll
  for (int nt = 0; nt < 4; ++nt) {
    int n = nt*16 + c;
    float bv = bf[layer*128 + 64 + n];
    floatx4 Acc = {bv, bv, bv, bv};
    half8 b0 = *(const half8*)&Wts[n*64 + (((q)   ^ (n&7))<<3)];
    half8 b1 = *(const half8*)&Wts[n*64 + (((4+q) ^ (n&7))<<3)];
    Acc = __builtin_amdgcn_mfma_f32_16x16x32_f16(c0, b0, Acc, 0, 0, 0);
    Acc = __builtin_amdgcn_mfma_f32_16x16x32_f16(c1, b1, Acc, 0, 0, 0);
    acc2[nt] = Acc;
  }

  #pragma unroll
  for (int nt = 0; nt < 4; ++nt) {
    int n = nt*16 + c;
    float og = ogb[layer*64 + n];
    float ob = ogb[NLAYERS*64 + layer*64 + n];
    #pragma unroll
    for (int r = 0; r < 4; ++r) {
      int m = mbase + q*4 + r;
      int gnode = b*64 + m;
      if (gnode < N_NODES) {
        float h = acc2[nt][r]; h = h > 0.f ? h : 0.f;
        float o = fmaf(og, h, ob);
        if (relu_out) {
          o = o > 0.f ? o : 0.f;
          outb[(size_t)gnode*CH + n] = (_Float16)o;
        } else {
          outf[(size_t)gnode*CH + n] = o;
        }
      }
    }
  }
}

extern "C" void kernel_launch(void* const* d_in, const int* in_sizes, int n_in,
                              void* d_out, int out_size, void* d_ws, size_t ws_size,
                              hipStream_t stream) {
  const float* x0  = (const float*)d_in[0];
  const int*   ei  = (const int*)d_in[1];
  const float* eps = (const float*)d_in[2];
  const float* W1  = (const float*)d_in[3];
  const float* b1  = (const float*)d_in[4];
  const float* g1  = (const float*)d_in[5];
  const float* be1 = (const float*)d_in[6];
  const float* W2  = (const float*)d_in[7];
  const float* b2  = (const float*)d_in[8];
  const float* g2  = (const float*)d_in[9];
  const float* be2 = (const float*)d_in[10];
  const float* bng = (const float*)d_in[11];
  const float* bnb = (const float*)d_in[12];
  const int* src = ei;
  const int* dst = ei + N_EDGES;
  float* OUT = (float*)d_out;

  char* p = (char*)d_ws;
  auto carve = [&](size_t bytes)->char*{ char* r = p; p += (bytes + 255) & ~(size_t)255; return r; };
  int*   offs    = (int*)carve((size_t)N_NODES*sizeof(int));
  int*   offe    = (int*)carve((size_t)N_NODES*sizeof(int));
  int*   btail   = (int*)carve(NBUCKC*sizeof(int));
  int*   ftail   = (int*)carve(NFINE*sizeof(int));
  int*   pairs   = (int*)carve((size_t)NBUCKC*SLABC*sizeof(int));        // 7.2 MB
  int*   pairs2  = (int*)carve((size_t)NFINE*SLABF*sizeof(int));         // 8.0 MB
  int*   srclist = (int*)carve((size_t)NFINE*SLABF*sizeof(int));         // 8.0 MB
  unsigned short* XB0 = (unsigned short*)carve((size_t)N_NODES*CH*2);    // 12.8 MB fp16
  unsigned short* XB1 = (unsigned short*)carve((size_t)N_NODES*CH*2);    // 12.8 MB fp16
  _Float16* Wt   = (_Float16*)carve((size_t)NLAYERS*2*4096*2);
  float* bfb     = (float*)carve((size_t)NLAYERS*2*64*sizeof(float));
  float* ogb     = (float*)carve((size_t)2*NLAYERS*64*sizeof(float));

  const int npart = (N_EDGES + EPB - 1)/EPB;   // 196
  binit_kernel<<<(NFINE+255)/256, 256, 0, stream>>>(btail, ftail);
  part1_kernel<<<npart, 256, 0, stream>>>(src, dst, btail, pairs);
  part2_kernel<<<NFINE, 256, 0, stream>>>(pairs, btail, ftail, pairs2);
  csr_kernel<<<NFINE, 256, 0, stream>>>(pairs2, ftail, offs, offe, srclist);
  prep_kernel<<<48, 256, 0, stream>>>(W1,b1,g1,be1,W2,b2,g2,be2,bng,bnb,Wt,bfb,ogb);
  xcvt_kernel<<<(N_NODES*CH/8 + 255)/256, 256, 0, stream>>>(x0, XB0);

  const int nlb = (N_NODES + 63)/64;   // 1563
  layer_kernel<<<nlb, 256, 0, stream>>>(XB0, offs, offe, srclist, eps, Wt, bfb, ogb, 0, OUT, (_Float16*)XB1, 1);
  layer_kernel<<<nlb, 256, 0, stream>>>(XB1, offs, offe, srclist, eps, Wt, bfb, ogb, 1, OUT, (_Float16*)XB0, 1);
  layer_kernel<<<nlb, 256, 0, stream>>>(XB0, offs, offe, srclist, eps, Wt, bfb, ogb, 2, OUT, (_Float16*)XB1, 0);
}

// Round 11
// 288.028 us; speedup vs baseline: 7.0651x; 1.0120x over previous
//
#include <hip/hip_runtime.h>
#include <hip/hip_fp16.h>

#define N_NODES 100000
#define N_EDGES 1600000
#define CH 64
#define NLAYERS 3
#define NBUCKC 98          // coarse buckets of 1024 dst nodes
#define SLABC 18432        // coarse slab capacity (mean 16327, sd 127 -> +16 sigma)
#define NFINE (NBUCKC*8)   // 784 fine buckets of 128 dst nodes
#define SLABF 2560         // fine slab capacity (mean 2048, sd 45 -> +11 sigma)
#define EPB 4096           // edges per part1 block (391 blocks; chunk ~42 edges, still line-dense)

typedef _Float16 half8 __attribute__((ext_vector_type(8)));
typedef float floatx4 __attribute__((ext_vector_type(4)));

static __device__ __forceinline__ float4 ld4(const float* p){ return *(const float4*)p; }
static __device__ __forceinline__ unsigned pack2(float a, float b){
  __half2 h = __float22half2_rn(make_float2(a, b));
  return *(unsigned*)&h;
}
static __device__ __forceinline__ half8 ldh8(const unsigned short* p){
  uint4 u = *(const uint4*)p;
  return *(half8*)&u;
}

// ---- tail init: coarse + fine slab cursors ----
__global__ __launch_bounds__(256) void binit_kernel(int* __restrict__ btail, int* __restrict__ ftail){
  int i = blockIdx.x*256 + threadIdx.x;
  if (i < NBUCKC) btail[i] = i*SLABC;
  if (i < NFINE)  ftail[i] = i*SLABF;
}

// ---- part1: edges -> 98 coarse slabs; packed = src | ((dst&1023)<<20) ----
__global__ __launch_bounds__(256) void part1_kernel(const int* __restrict__ src, const int* __restrict__ dst,
                                                    int* __restrict__ btail, int* __restrict__ pairs){
  __shared__ int lpos[NBUCKC];
  __shared__ int gb[NBUCKC];
  int tid = threadIdx.x;
  if (tid < NBUCKC) lpos[tid] = 0;
  __syncthreads();
  int base = blockIdx.x * EPB;
  #pragma unroll 4
  for (int k = 0; k < EPB/256; ++k) {
    int e = base + k*256 + tid;
    if (e < N_EDGES) atomicAdd(&lpos[dst[e] >> 10], 1);
  }
  __syncthreads();
  if (tid < NBUCKC) {
    int cc = lpos[tid];
    gb[tid] = cc ? atomicAdd(&btail[tid], cc) : 0;
    lpos[tid] = 0;
  }
  __syncthreads();
  #pragma unroll 4
  for (int k = 0; k < EPB/256; ++k) {
    int e = base + k*256 + tid;
    if (e < N_EDGES) {
      int d = dst[e];
      int bk = d >> 10;
      int p = atomicAdd(&lpos[bk], 1);
      int idx = gb[bk] + p;
      if (idx < (bk+1)*SLABC)                   // memory-safety clamp (statistically never)
        pairs[idx] = src[e] | ((d & 1023) << 20);
    }
  }
}

// ---- part2: split each coarse slab into 8 fine sub-slabs (784 blocks, 1/8 edge-segment each) ----
__global__ __launch_bounds__(256) void part2_kernel(const int* __restrict__ pairs, const int* __restrict__ btail,
                                                    int* __restrict__ ftail, int* __restrict__ pairs2){
  __shared__ int cnt[8*32];
  __shared__ int scur[8];
  int tid = threadIdx.x;
  int b = blockIdx.x >> 3;        // coarse bucket
  int sg = blockIdx.x & 7;        // segment of the slab's edge range
  int e0 = b*SLABC;
  int e1 = btail[b]; int emax = e0 + SLABC; if (e1 > emax) e1 = emax;
  int len = e1 - e0;
  int s0 = e0 + (int)(((long)len * sg) >> 3);
  int s1 = e0 + (int)(((long)len * (sg+1)) >> 3);
  cnt[tid] = 0;
  __syncthreads();
  for (int i = s0 + tid; i < s1; i += 256) {
    int p = pairs[i];
    int fk = ((unsigned)p >> 27);
    atomicAdd(&cnt[(fk<<5) + (tid & 31)], 1);
  }
  __syncthreads();
  if (tid < 8) {
    int tot = 0;
    #pragma unroll
    for (int r = 0; r < 32; ++r) tot += cnt[(tid<<5) + r];
    scur[tid] = tot ? atomicAdd(&ftail[(b<<3) + tid], tot) : 0;
  }
  __syncthreads();
  int lane = tid & 63;
  for (int i = s0 + (tid >> 6)*64; i < s1; i += 256) {
    int my = i + lane;
    bool valid = (my < s1);
    int p = valid ? pairs[my] : 0;
    int fk = valid ? (int)((unsigned)p >> 27) : -1;
    #pragma unroll
    for (int j = 0; j < 8; ++j) {
      unsigned long long mask = __ballot(valid && fk == j);
      if (mask) {
        int leader = __ffsll((long long)mask) - 1;
        int cc = __popcll(mask);
        int basep = 0;
        if (lane == leader) basep = atomicAdd(&scur[j], cc);
        basep = __shfl(basep, leader, 64);
        if (valid && fk == j) {
          int rank = __popcll(mask & ((1ull << lane) - 1ull));
          int pos = basep + rank;
          if (pos < ((b<<3) + j + 1)*SLABF)     // memory-safety clamp
            pairs2[pos] = p;
        }
      }
    }
  }
}

// ---- csr: per fine sub-slab (784 blocks): hist 128 nodes, scan, scatter ----
__global__ __launch_bounds__(256) void csr_kernel(const int* __restrict__ pairs2, const int* __restrict__ ftail,
                                                  int* __restrict__ offs, int* __restrict__ offe,
                                                  int* __restrict__ srclist){
  __shared__ int c[128];
  __shared__ int s[128];
  __shared__ int cur[128];
  int t = threadIdx.x;
  int f = blockIdx.x;
  int e0 = f*SLABF;
  int e1 = ftail[f]; int emax = e0 + SLABF; if (e1 > emax) e1 = emax;
  if (t < 128) c[t] = 0;
  __syncthreads();
  for (int i = e0 + t; i < e1; i += 256) {
    int p = pairs2[i];
    atomicAdd(&c[((unsigned)p >> 20) & 127], 1);
  }
  __syncthreads();
  int v = (t < 128) ? c[t] : 0;
  if (t < 128) s[t] = v;
  __syncthreads();
  #pragma unroll
  for (int o = 1; o < 128; o <<= 1){
    int u = 0;
    if (t < 128 && t >= o) u = s[t-o];
    __syncthreads();
    if (t < 128) s[t] += u;
    __syncthreads();
  }
  if (t < 128) {
    int excl = s[t] - v;
    cur[t] = excl;
    int n = (f >> 3)*1024 + (f & 7)*128 + t;
    if (n < N_NODES) { offs[n] = e0 + excl; offe[n] = e0 + excl + v; }
  }
  __syncthreads();
  for (int i = e0 + t; i < e1; i += 256) {
    int p = pairs2[i];
    int pos = atomicAdd(&cur[((unsigned)p >> 20) & 127], 1);
    if (pos < SLABF)                            // memory-safety clamp
      srclist[e0 + pos] = p & 0xFFFFF;
  }
}

// ---- fold BN into weights (fp16, transposed, XOR-swizzled) and biases (fp32) ----
__global__ __launch_bounds__(256) void prep_kernel(
    const float* __restrict__ W1, const float* __restrict__ b1,
    const float* __restrict__ g1, const float* __restrict__ be1,
    const float* __restrict__ W2, const float* __restrict__ b2,
    const float* __restrict__ g2, const float* __restrict__ be2,
    const float* __restrict__ bng, const float* __restrict__ bnb,
    _Float16* __restrict__ Wt, float* __restrict__ bf, float* __restrict__ ogb){
  const float s = 0.9999950000374997f;   // 1/sqrt(1+1e-5)
  int i = blockIdx.x*256 + threadIdx.x;
  if (i < NLAYERS*4096) {
    int l = i >> 12, rem = i & 4095, k = rem >> 6, n = rem & 63;
    int di = n*64 + (((k>>3) ^ (n&7))<<3) + (k&7);
    Wt[l*8192 + di]        = (_Float16)(W1[i] * g1[l*64+n] * s);
    Wt[l*8192 + 4096 + di] = (_Float16)(W2[i] * g2[l*64+n] * s);
  }
  if (i < NLAYERS*64) {
    int l = i >> 6, j = i & 63;
    bf[l*128 + j]      = b1[i]*g1[i]*s + be1[i];
    bf[l*128 + 64 + j] = b2[i]*g2[i]*s + be2[i];
    ogb[i]                 = bng[i]*s;
    ogb[NLAYERS*64 + i]    = bnb[i];
  }
}

// ---- x0 (fp32) -> XB0 (fp16) ----
__global__ __launch_bounds__(256) void xcvt_kernel(const float* __restrict__ x, unsigned short* __restrict__ xb){
  int i = (blockIdx.x*256 + threadIdx.x)*8;
  if (i < N_NODES*CH) {
    float4 v0 = ld4(x + i), v1 = ld4(x + i + 4);
    uint4 w;
    w.x = pack2(v0.x, v0.y); w.y = pack2(v0.z, v0.w);
    w.z = pack2(v1.x, v1.y); w.w = pack2(v1.z, v1.w);
    *(uint4*)(xb + i) = w;
  }
}

// ---- fused layer: gather (8 true chains @128 VGPR) -> MFMA MLP -> epilogue ----
// launch_bounds(256,4): VGPR cap 128 so all 8 gather chains stay in flight (60-VGPR build serialized them).
__global__ __launch_bounds__(256, 4) void layer_kernel(const unsigned short* __restrict__ XBin,
                                                    const int* __restrict__ offs, const int* __restrict__ offe,
                                                    const int* __restrict__ srclist,
                                                    const float* __restrict__ eps,
                                                    const _Float16* __restrict__ Wt,
                                                    const float* __restrict__ bf, const float* __restrict__ ogb,
                                                    int layer, float* __restrict__ outf,
                                                    _Float16* __restrict__ outb, int relu_out){
  __shared__ _Float16 HsA[64*64];
  __shared__ _Float16 Wts[64*64];
  int tid = threadIdx.x;
  int b = blockIdx.x;
  const _Float16* Wg = Wt + layer*8192;
  *(uint4*)&Wts[tid*8]       = *(const uint4*)&Wg[tid*8];
  *(uint4*)&Wts[(tid+256)*8] = *(const uint4*)&Wg[(tid+256)*8];

  float ep = 1.0f + eps[layer];
  int kb = tid & 7;
  const unsigned short* xr = XBin + (kb << 3);
  #pragma unroll
  for (int p = 0; p < 2; ++p) {
    int nl = p*32 + (tid >> 3);
    int n = b*64 + nl;
    float r[8] = {0,0,0,0,0,0,0,0};
    if (n < N_NODES) {
      half8 A = (half8)(_Float16)0, B = A, C = A, D = A, E = A, F = A, G = A, H = A;
      int e0 = offs[n], e1 = offe[n];
      int e = e0;
      for (; e+8 <= e1; e += 8) {            // 8 independent chains, 8 loads in flight
        int s0 = srclist[e],   s1 = srclist[e+1], s2 = srclist[e+2], s3 = srclist[e+3];
        int s4 = srclist[e+4], s5 = srclist[e+5], s6 = srclist[e+6], s7 = srclist[e+7];
        half8 u0 = ldh8(xr + (s0<<6));
        half8 u1 = ldh8(xr + (s1<<6));
        half8 u2 = ldh8(xr + (s2<<6));
        half8 u3 = ldh8(xr + (s3<<6));
        half8 u4 = ldh8(xr + (s4<<6));
        half8 u5 = ldh8(xr + (s5<<6));
        half8 u6 = ldh8(xr + (s6<<6));
        half8 u7 = ldh8(xr + (s7<<6));
        A += u0; B += u1; C += u2; D += u3; E += u4; F += u5; G += u6; H += u7;
      }
      for (; e+4 <= e1; e += 4) {
        int s0 = srclist[e], s1 = srclist[e+1], s2 = srclist[e+2], s3 = srclist[e+3];
        half8 u0 = ldh8(xr + (s0<<6));
        half8 u1 = ldh8(xr + (s1<<6));
        half8 u2 = ldh8(xr + (s2<<6));
        half8 u3 = ldh8(xr + (s3<<6));
        A += u0; B += u1; C += u2; D += u3;
      }
      for (; e < e1; ++e) {
        A += ldh8(xr + (srclist[e]<<6));
      }
      half8 S = ((A + B) + (C + D)) + ((E + F) + (G + H));
      half8 sv = ldh8(xr + (n<<6));
      #pragma unroll
      for (int i = 0; i < 8; ++i) r[i] = fmaf(ep, (float)sv[i], (float)S[i]);
    }
    uint4 w;
    w.x = pack2(r[0], r[1]); w.y = pack2(r[2], r[3]);
    w.z = pack2(r[4], r[5]); w.w = pack2(r[6], r[7]);
    *(uint4*)&HsA[nl*64 + ((kb ^ (nl&7))<<3)] = w;
  }
  __syncthreads();

  int lane = tid & 63;
  int wid = tid >> 6;
  int c = lane & 15;
  int q = lane >> 4;
  int mbase = wid*16;
  int ma = mbase + c;

  half8 a0 = *(const half8*)&HsA[ma*64 + (((q)   ^ (ma&7))<<3)];
  half8 a1 = *(const half8*)&HsA[ma*64 + (((4+q) ^ (ma&7))<<3)];

  floatx4 acc[4];
  #pragma unroll
  for (int nt = 0; nt < 4; ++nt) {
    int n = nt*16 + c;
    float bv = bf[layer*128 + n];
    floatx4 Acc = {bv, bv, bv, bv};
    half8 b0 = *(const half8*)&Wts[n*64 + (((q)   ^ (n&7))<<3)];
    half8 b1 = *(const half8*)&Wts[n*64 + (((4+q) ^ (n&7))<<3)];
    Acc = __builtin_amdgcn_mfma_f32_16x16x32_f16(a0, b0, Acc, 0, 0, 0);
    Acc = __builtin_amdgcn_mfma_f32_16x16x32_f16(a1, b1, Acc, 0, 0, 0);
    acc[nt] = Acc;
  }
  __syncthreads();

  #pragma unroll
  for (int nt = 0; nt < 4; ++nt) {
    int n = nt*16 + c;
    #pragma unroll
    for (int r = 0; r < 4; ++r) {
      int m = mbase + q*4 + r;
      float h = acc[nt][r]; h = h > 0.f ? h : 0.f;
      HsA[m*64 + (((n>>3) ^ (m&7))<<3) + (n&7)] = (_Float16)h;
    }
  }
  *(uint4*)&Wts[tid*8]       = *(const uint4*)&Wg[4096 + tid*8];
  *(uint4*)&Wts[(tid+256)*8] = *(const uint4*)&Wg[4096 + (tid+256)*8];
  __syncthreads();

  half8 c0 = *(const half8*)&HsA[ma*64 + (((q)   ^ (ma&7))<<3)];
  half8 c1 = *(const half8*)&HsA[ma*64 + (((4+q) ^ (ma&7))<<3)];
  floatx4 acc2[4];
  #pragma unroll
  for (int nt = 0; nt < 4; ++nt) {
    int n = nt*16 + c;
    float bv = bf[layer*128 + 64 + n];
    floatx4 Acc = {bv, bv, bv, bv};
    half8 b0 = *(const half8*)&Wts[n*64 + (((q)   ^ (n&7))<<3)];
    half8 b1 = *(const half8*)&Wts[n*64 + (((4+q) ^ (n&7))<<3)];
    Acc = __builtin_amdgcn_mfma_f32_16x16x32_f16(c0, b0, Acc, 0, 0, 0);
    Acc = __builtin_amdgcn_mfma_f32_16x16x32_f16(c1, b1, Acc, 0, 0, 0);
    acc2[nt] = Acc;
  }

  #pragma unroll
  for (int nt = 0; nt < 4; ++nt) {
    int n = nt*16 + c;
    float og = ogb[layer*64 + n];
    float ob = ogb[NLAYERS*64 + layer*64 + n];
    #pragma unroll
    for (int r = 0; r < 4; ++r) {
      int m = mbase + q*4 + r;
      int gnode = b*64 + m;
      if (gnode < N_NODES) {
        float h = acc2[nt][r]; h = h > 0.f ? h : 0.f;
        float o = fmaf(og, h, ob);
        if (relu_out) {
          o = o > 0.f ? o : 0.f;
          outb[(size_t)gnode*CH + n] = (_Float16)o;
        } else {
          outf[(size_t)gnode*CH + n] = o;
        }
      }
    }
  }
}

extern "C" void kernel_launch(void* const* d_in, const int* in_sizes, int n_in,
                              void* d_out, int out_size, void* d_ws, size_t ws_size,
                              hipStream_t stream) {
  const float* x0  = (const float*)d_in[0];
  const int*   ei  = (const int*)d_in[1];
  const float* eps = (const float*)d_in[2];
  const float* W1  = (const float*)d_in[3];
  const float* b1  = (const float*)d_in[4];
  const float* g1  = (const float*)d_in[5];
  const float* be1 = (const float*)d_in[6];
  const float* W2  = (const float*)d_in[7];
  const float* b2  = (const float*)d_in[8];
  const float* g2  = (const float*)d_in[9];
  const float* be2 = (const float*)d_in[10];
  const float* bng = (const float*)d_in[11];
  const float* bnb = (const float*)d_in[12];
  const int* src = ei;
  const int* dst = ei + N_EDGES;
  float* OUT = (float*)d_out;

  char* p = (char*)d_ws;
  auto carve = [&](size_t bytes)->char*{ char* r = p; p += (bytes + 255) & ~(size_t)255; return r; };
  int*   offs    = (int*)carve((size_t)N_NODES*sizeof(int));
  int*   offe    = (int*)carve((size_t)N_NODES*sizeof(int));
  int*   btail   = (int*)carve(NBUCKC*sizeof(int));
  int*   ftail   = (int*)carve(NFINE*sizeof(int));
  int*   pairs   = (int*)carve((size_t)NBUCKC*SLABC*sizeof(int));        // 7.2 MB
  int*   pairs2  = (int*)carve((size_t)NFINE*SLABF*sizeof(int));         // 8.0 MB
  int*   srclist = (int*)carve((size_t)NFINE*SLABF*sizeof(int));         // 8.0 MB
  unsigned short* XB0 = (unsigned short*)carve((size_t)N_NODES*CH*2);    // 12.8 MB fp16
  unsigned short* XB1 = (unsigned short*)carve((size_t)N_NODES*CH*2);    // 12.8 MB fp16
  _Float16* Wt   = (_Float16*)carve((size_t)NLAYERS*2*4096*2);
  float* bfb     = (float*)carve((size_t)NLAYERS*2*64*sizeof(float));
  float* ogb     = (float*)carve((size_t)2*NLAYERS*64*sizeof(float));

  const int npart = (N_EDGES + EPB - 1)/EPB;   // 391
  binit_kernel<<<(NFINE+255)/256, 256, 0, stream>>>(btail, ftail);
  part1_kernel<<<npart, 256, 0, stream>>>(src, dst, btail, pairs);
  part2_kernel<<<NFINE, 256, 0, stream>>>(pairs, btail, ftail, pairs2);
  csr_kernel<<<NFINE, 256, 0, stream>>>(pairs2, ftail, offs, offe, srclist);
  prep_kernel<<<48, 256, 0, stream>>>(W1,b1,g1,be1,W2,b2,g2,be2,bng,bnb,Wt,bfb,ogb);
  xcvt_kernel<<<(N_NODES*CH/8 + 255)/256, 256, 0, stream>>>(x0, XB0);

  const int nlb = (N_NODES + 63)/64;   // 1563
  layer_kernel<<<nlb, 256, 0, stream>>>(XB0, offs, offe, srclist, eps, Wt, bfb, ogb, 0, OUT, (_Float16*)XB1, 1);
  layer_kernel<<<nlb, 256, 0, stream>>>(XB1, offs, offe, srclist, eps, Wt, bfb, ogb, 1, OUT, (_Float16*)XB0, 1);
  layer_kernel<<<nlb, 256, 0, stream>>>(XB0, offs, offe, srclist, eps, Wt, bfb, ogb, 2, OUT, (_Float16*)XB1, 0);
}

// Round 12
// 285.116 us; speedup vs baseline: 7.1373x; 1.0102x over previous
//
#include <hip/hip_runtime.h>
#include <hip/hip_fp16.h>

#define N_NODES 100000
#define N_EDGES 1600000
#define CH 64
#define NLAYERS 3
#define NBUCKC 98          // coarse buckets of 1024 dst nodes
#define SLABC 18432        // coarse slab capacity (mean 16327, sd 127 -> +16 sigma)
#define NFINE (NBUCKC*8)   // 784 fine buckets of 128 dst nodes
#define SLABF 2560         // fine slab capacity (mean 2048, sd 45 -> +11 sigma)
#define EPB 4096           // edges per part1 block (391 blocks)

typedef _Float16 half8 __attribute__((ext_vector_type(8)));
typedef float floatx4 __attribute__((ext_vector_type(4)));

static __device__ __forceinline__ float4 ld4(const float* p){ return *(const float4*)p; }
static __device__ __forceinline__ unsigned pack2(float a, float b){
  __half2 h = __float22half2_rn(make_float2(a, b));
  return *(unsigned*)&h;
}
static __device__ __forceinline__ half8 ldh8(const unsigned short* p){
  uint4 u = *(const uint4*)p;
  return *(half8*)&u;
}

// ---- part1: single-pass partition into 98 coarse slabs; packed = src | ((dst&1023)<<20) ----
__global__ __launch_bounds__(256) void part1_kernel(const int* __restrict__ src, const int* __restrict__ dst,
                                                    int* __restrict__ btail, int* __restrict__ pairs){
  __shared__ int lpos[NBUCKC];
  __shared__ int gb[NBUCKC];
  int tid = threadIdx.x;
  if (tid < NBUCKC) lpos[tid] = 0;
  __syncthreads();
  int base = blockIdx.x * EPB;
  int es[EPB/256], ed[EPB/256], er[EPB/256];
  #pragma unroll
  for (int k = 0; k < EPB/256; ++k) {
    int e = base + k*256 + tid;
    if (e < N_EDGES) {
      es[k] = src[e];
      ed[k] = dst[e];
      er[k] = atomicAdd(&lpos[ed[k] >> 10], 1);
    }
  }
  __syncthreads();
  if (tid < NBUCKC) {
    int cc = lpos[tid];
    gb[tid] = cc ? atomicAdd(&btail[tid], cc) : 0;
  }
  __syncthreads();
  #pragma unroll
  for (int k = 0; k < EPB/256; ++k) {
    int e = base + k*256 + tid;
    if (e < N_EDGES) {
      int bk = ed[k] >> 10;
      int idx = gb[bk] + er[k];
      if (idx < (bk+1)*SLABC)                   // memory-safety clamp (statistically never)
        pairs[idx] = es[k] | ((ed[k] & 1023) << 20);
    }
  }
}

// ---- part2: split each coarse slab into 8 fine sub-slabs (784 blocks, 1/8 edge-segment each) ----
__global__ __launch_bounds__(256) void part2_kernel(const int* __restrict__ pairs, const int* __restrict__ btail,
                                                    int* __restrict__ ftail, int* __restrict__ pairs2){
  __shared__ int cnt[8*32];
  __shared__ int scur[8];
  int tid = threadIdx.x;
  int b = blockIdx.x >> 3;
  int sg = blockIdx.x & 7;
  int e0 = b*SLABC;
  int e1 = btail[b]; int emax = e0 + SLABC; if (e1 > emax) e1 = emax;
  int len = e1 - e0;
  int s0 = e0 + (int)(((long)len * sg) >> 3);
  int s1 = e0 + (int)(((long)len * (sg+1)) >> 3);
  cnt[tid] = 0;
  __syncthreads();
  for (int i = s0 + tid; i < s1; i += 256) {
    int p = pairs[i];
    int fk = ((unsigned)p >> 27);
    atomicAdd(&cnt[(fk<<5) + (tid & 31)], 1);
  }
  __syncthreads();
  if (tid < 8) {
    int tot = 0;
    #pragma unroll
    for (int r = 0; r < 32; ++r) tot += cnt[(tid<<5) + r];
    scur[tid] = tot ? atomicAdd(&ftail[(b<<3) + tid], tot) : 0;
  }
  __syncthreads();
  int lane = tid & 63;
  for (int i = s0 + (tid >> 6)*64; i < s1; i += 256) {
    int my = i + lane;
    bool valid = (my < s1);
    int p = valid ? pairs[my] : 0;
    int fk = valid ? (int)((unsigned)p >> 27) : -1;
    #pragma unroll
    for (int j = 0; j < 8; ++j) {
      unsigned long long mask = __ballot(valid && fk == j);
      if (mask) {
        int leader = __ffsll((long long)mask) - 1;
        int cc = __popcll(mask);
        int basep = 0;
        if (lane == leader) basep = atomicAdd(&scur[j], cc);
        basep = __shfl(basep, leader, 64);
        if (valid && fk == j) {
          int rank = __popcll(mask & ((1ull << lane) - 1ull));
          int pos = basep + rank;
          if (pos < ((b<<3) + j + 1)*SLABF)     // memory-safety clamp
            pairs2[pos] = p;
        }
      }
    }
  }
}

// ---- csr: per fine sub-slab (784 blocks): hist 128 nodes, scan, scatter ----
__global__ __launch_bounds__(256) void csr_kernel(const int* __restrict__ pairs2, const int* __restrict__ ftail,
                                                  int* __restrict__ offs, int* __restrict__ offe,
                                                  int* __restrict__ srclist){
  __shared__ int c[128];
  __shared__ int s[128];
  __shared__ int cur[128];
  int t = threadIdx.x;
  int f = blockIdx.x;
  int e0 = f*SLABF;
  int e1 = ftail[f]; int emax = e0 + SLABF; if (e1 > emax) e1 = emax;
  if (t < 128) c[t] = 0;
  __syncthreads();
  for (int i = e0 + t; i < e1; i += 256) {
    int p = pairs2[i];
    atomicAdd(&c[((unsigned)p >> 20) & 127], 1);
  }
  __syncthreads();
  int v = (t < 128) ? c[t] : 0;
  if (t < 128) s[t] = v;
  __syncthreads();
  #pragma unroll
  for (int o = 1; o < 128; o <<= 1){
    int u = 0;
    if (t < 128 && t >= o) u = s[t-o];
    __syncthreads();
    if (t < 128) s[t] += u;
    __syncthreads();
  }
  if (t < 128) {
    int excl = s[t] - v;
    cur[t] = excl;
    int n = (f >> 3)*1024 + (f & 7)*128 + t;
    if (n < N_NODES) { offs[n] = e0 + excl; offe[n] = e0 + excl + v; }
  }
  __syncthreads();
  for (int i = e0 + t; i < e1; i += 256) {
    int p = pairs2[i];
    int pos = atomicAdd(&cur[((unsigned)p >> 20) & 127], 1);
    if (pos < SLABF)                            // memory-safety clamp
      srclist[e0 + pos] = p & 0xFFFFF;
  }
}

// ---- setup: slab cursor init + fold BN into weights (fp16, transposed, XOR-swizzled) ----
__global__ __launch_bounds__(256) void prep_kernel(
    const float* __restrict__ W1, const float* __restrict__ b1,
    const float* __restrict__ g1, const float* __restrict__ be1,
    const float* __restrict__ W2, const float* __restrict__ b2,
    const float* __restrict__ g2, const float* __restrict__ be2,
    const float* __restrict__ bng, const float* __restrict__ bnb,
    _Float16* __restrict__ Wt, float* __restrict__ bf, float* __restrict__ ogb,
    int* __restrict__ btail, int* __restrict__ ftail){
  const float s = 0.9999950000374997f;   // 1/sqrt(1+1e-5)
  int i = blockIdx.x*256 + threadIdx.x;
  if (i < NBUCKC) btail[i] = i*SLABC;
  if (i < NFINE)  ftail[i] = i*SLABF;
  if (i < NLAYERS*4096) {
    int l = i >> 12, rem = i & 4095, k = rem >> 6, n = rem & 63;
    int di = n*64 + (((k>>3) ^ (n&7))<<3) + (k&7);
    Wt[l*8192 + di]        = (_Float16)(W1[i] * g1[l*64+n] * s);
    Wt[l*8192 + 4096 + di] = (_Float16)(W2[i] * g2[l*64+n] * s);
  }
  if (i < NLAYERS*64) {
    int l = i >> 6, j = i & 63;
    bf[l*128 + j]      = b1[i]*g1[i]*s + be1[i];
    bf[l*128 + 64 + j] = b2[i]*g2[i]*s + be2[i];
    ogb[i]                 = bng[i]*s;
    ogb[NLAYERS*64 + i]    = bnb[i];
  }
}

// ---- x0 (fp32) -> XB0 (fp16) ----
__global__ __launch_bounds__(256) void xcvt_kernel(const float* __restrict__ x, unsigned short* __restrict__ xb){
  int i = (blockIdx.x*256 + threadIdx.x)*8;
  if (i < N_NODES*CH) {
    float4 v0 = ld4(x + i), v1 = ld4(x + i + 4);
    uint4 w;
    w.x = pack2(v0.x, v0.y); w.y = pack2(v0.z, v0.w);
    w.z = pack2(v1.x, v1.y); w.w = pack2(v1.z, v1.w);
    *(uint4*)(xb + i) = w;
  }
}

// ---- fused layer: SW-pipelined gather (8 chains, double-buffered batches) -> MFMA MLP ----
__global__ __launch_bounds__(256, 4) void layer_kernel(const unsigned short* __restrict__ XBin,
                                                    const int* __restrict__ offs, const int* __restrict__ offe,
                                                    const int* __restrict__ srclist,
                                                    const float* __restrict__ eps,
                                                    const _Float16* __restrict__ Wt,
                                                    const float* __restrict__ bf, const float* __restrict__ ogb,
                                                    int layer, float* __restrict__ outf,
                                                    _Float16* __restrict__ outb, int relu_out){
  __shared__ _Float16 HsA[64*64];
  __shared__ _Float16 Wts[64*64];
  int tid = threadIdx.x;
  int b = blockIdx.x;
  const _Float16* Wg = Wt + layer*8192;
  *(uint4*)&Wts[tid*8]       = *(const uint4*)&Wg[tid*8];
  *(uint4*)&Wts[(tid+256)*8] = *(const uint4*)&Wg[(tid+256)*8];

  float ep = 1.0f + eps[layer];
  int kb = tid & 7;
  const unsigned short* xr = XBin + (kb << 3);
  #pragma unroll
  for (int p = 0; p < 2; ++p) {
    int nl = p*32 + (tid >> 3);
    int n = b*64 + nl;
    float r[8] = {0,0,0,0,0,0,0,0};
    if (n < N_NODES) {
      half8 A = (half8)(_Float16)0, B = A, C = A, D = A, E = A, F = A, G = A, H = A;
      int e0 = offs[n], e1 = offe[n];
      int e = e0;
      if (e + 8 <= e1) {
        // prologue: batch 0 in flight
        half8 u0 = ldh8(xr + (srclist[e  ]<<6));
        half8 u1 = ldh8(xr + (srclist[e+1]<<6));
        half8 u2 = ldh8(xr + (srclist[e+2]<<6));
        half8 u3 = ldh8(xr + (srclist[e+3]<<6));
        half8 u4 = ldh8(xr + (srclist[e+4]<<6));
        half8 u5 = ldh8(xr + (srclist[e+5]<<6));
        half8 u6 = ldh8(xr + (srclist[e+6]<<6));
        half8 u7 = ldh8(xr + (srclist[e+7]<<6));
        e += 8;
        // steady state: issue batch i+1, then consume batch i
        for (; e + 8 <= e1; e += 8) {
          half8 v0 = ldh8(xr + (srclist[e  ]<<6));
          half8 v1 = ldh8(xr + (srclist[e+1]<<6));
          half8 v2 = ldh8(xr + (srclist[e+2]<<6));
          half8 v3 = ldh8(xr + (srclist[e+3]<<6));
          half8 v4 = ldh8(xr + (srclist[e+4]<<6));
          half8 v5 = ldh8(xr + (srclist[e+5]<<6));
          half8 v6 = ldh8(xr + (srclist[e+6]<<6));
          half8 v7 = ldh8(xr + (srclist[e+7]<<6));
          A += u0; B += u1; C += u2; D += u3;
          E += u4; F += u5; G += u6; H += u7;
          u0 = v0; u1 = v1; u2 = v2; u3 = v3;
          u4 = v4; u5 = v5; u6 = v6; u7 = v7;
        }
        A += u0; B += u1; C += u2; D += u3;
        E += u4; F += u5; G += u6; H += u7;
      }
      for (; e+4 <= e1; e += 4) {
        half8 u0 = ldh8(xr + (srclist[e  ]<<6));
        half8 u1 = ldh8(xr + (srclist[e+1]<<6));
        half8 u2 = ldh8(xr + (srclist[e+2]<<6));
        half8 u3 = ldh8(xr + (srclist[e+3]<<6));
        A += u0; B += u1; C += u2; D += u3;
      }
      for (; e < e1; ++e) {
        A += ldh8(xr + (srclist[e]<<6));
      }
      half8 S = ((A + B) + (C + D)) + ((E + F) + (G + H));
      half8 sv = ldh8(xr + (n<<6));
      #pragma unroll
      for (int i = 0; i < 8; ++i) r[i] = fmaf(ep, (float)sv[i], (float)S[i]);
    }
    uint4 w;
    w.x = pack2(r[0], r[1]); w.y = pack2(r[2], r[3]);
    w.z = pack2(r[4], r[5]); w.w = pack2(r[6], r[7]);
    *(uint4*)&HsA[nl*64 + ((kb ^ (nl&7))<<3)] = w;
  }
  __syncthreads();

  int lane = tid & 63;
  int wid = tid >> 6;
  int c = lane & 15;
  int q = lane >> 4;
  int mbase = wid*16;
  int ma = mbase + c;

  half8 a0 = *(const half8*)&HsA[ma*64 + (((q)   ^ (ma&7))<<3)];
  half8 a1 = *(const half8*)&HsA[ma*64 + (((4+q) ^ (ma&7))<<3)];

  floatx4 acc[4];
  #pragma unroll
  for (int nt = 0; nt < 4; ++nt) {
    int n = nt*16 + c;
    float bv = bf[layer*128 + n];
    floatx4 Acc = {bv, bv, bv, bv};
    half8 b0 = *(const half8*)&Wts[n*64 + (((q)   ^ (n&7))<<3)];
    half8 b1 = *(const half8*)&Wts[n*64 + (((4+q) ^ (n&7))<<3)];
    Acc = __builtin_amdgcn_mfma_f32_16x16x32_f16(a0, b0, Acc, 0, 0, 0);
    Acc = __builtin_amdgcn_mfma_f32_16x16x32_f16(a1, b1, Acc, 0, 0, 0);
    acc[nt] = Acc;
  }
  __syncthreads();

  #pragma unroll
  for (int nt = 0; nt < 4; ++nt) {
    int n = nt*16 + c;
    #pragma unroll
    for (int r = 0; r < 4; ++r) {
      int m = mbase + q*4 + r;
      float h = acc[nt][r]; h = h > 0.f ? h : 0.f;
      HsA[m*64 + (((n>>3) ^ (m&7))<<3) + (n&7)] = (_Float16)h;
    }
  }
  *(uint4*)&Wts[tid*8]       = *(const uint4*)&Wg[4096 + tid*8];
  *(uint4*)&Wts[(tid+256)*8] = *(const uint4*)&Wg[4096 + (tid+256)*8];
  __syncthreads();

  half8 c0 = *(const half8*)&HsA[ma*64 + (((q)   ^ (ma&7))<<3)];
  half8 c1 = *(const half8*)&HsA[ma*64 + (((4+q) ^ (ma&7))<<3)];
  floatx4 acc2[4];
  #pragma unroll
  for (int nt = 0; nt < 4; ++nt) {
    int n = nt*16 + c;
    float bv = bf[layer*128 + 64 + n];
    floatx4 Acc = {bv, bv, bv, bv};
    half8 b0 = *(const half8*)&Wts[n*64 + (((q)   ^ (n&7))<<3)];
    half8 b1 = *(const half8*)&Wts[n*64 + (((4+q) ^ (n&7))<<3)];
    Acc = __builtin_amdgcn_mfma_f32_16x16x32_f16(c0, b0, Acc, 0, 0, 0);
    Acc = __builtin_amdgcn_mfma_f32_16x16x32_f16(c1, b1, Acc, 0, 0, 0);
    acc2[nt] = Acc;
  }

  #pragma unroll
  for (int nt = 0; nt < 4; ++nt) {
    int n = nt*16 + c;
    float og = ogb[layer*64 + n];
    float ob = ogb[NLAYERS*64 + layer*64 + n];
    #pragma unroll
    for (int r = 0; r < 4; ++r) {
      int m = mbase + q*4 + r;
      int gnode = b*64 + m;
      if (gnode < N_NODES) {
        float h = acc2[nt][r]; h = h > 0.f ? h : 0.f;
        float o = fmaf(og, h, ob);
        if (relu_out) {
          o = o > 0.f ? o : 0.f;
          outb[(size_t)gnode*CH + n] = (_Float16)o;
        } else {
          outf[(size_t)gnode*CH + n] = o;
        }
      }
    }
  }
}

extern "C" void kernel_launch(void* const* d_in, const int* in_sizes, int n_in,
                              void* d_out, int out_size, void* d_ws, size_t ws_size,
                              hipStream_t stream) {
  const float* x0  = (const float*)d_in[0];
  const int*   ei  = (const int*)d_in[1];
  const float* eps = (const float*)d_in[2];
  const float* W1  = (const float*)d_in[3];
  const float* b1  = (const float*)d_in[4];
  const float* g1  = (const float*)d_in[5];
  const float* be1 = (const float*)d_in[6];
  const float* W2  = (const float*)d_in[7];
  const float* b2  = (const float*)d_in[8];
  const float* g2  = (const float*)d_in[9];
  const float* be2 = (const float*)d_in[10];
  const float* bng = (const float*)d_in[11];
  const float* bnb = (const float*)d_in[12];
  const int* src = ei;
  const int* dst = ei + N_EDGES;
  float* OUT = (float*)d_out;

  char* p = (char*)d_ws;
  auto carve = [&](size_t bytes)->char*{ char* r = p; p += (bytes + 255) & ~(size_t)255; return r; };
  int*   offs    = (int*)carve((size_t)N_NODES*sizeof(int));
  int*   offe    = (int*)carve((size_t)N_NODES*sizeof(int));
  int*   btail   = (int*)carve(NBUCKC*sizeof(int));
  int*   ftail   = (int*)carve(NFINE*sizeof(int));
  int*   pairs   = (int*)carve((size_t)NBUCKC*SLABC*sizeof(int));        // 7.2 MB
  int*   pairs2  = (int*)carve((size_t)NFINE*SLABF*sizeof(int));         // 8.0 MB
  int*   srclist = (int*)carve((size_t)NFINE*SLABF*sizeof(int));         // 8.0 MB
  unsigned short* XB0 = (unsigned short*)carve((size_t)N_NODES*CH*2);    // 12.8 MB fp16
  unsigned short* XB1 = (unsigned short*)carve((size_t)N_NODES*CH*2);    // 12.8 MB fp16
  _Float16* Wt   = (_Float16*)carve((size_t)NLAYERS*2*4096*2);
  float* bfb     = (float*)carve((size_t)NLAYERS*2*64*sizeof(float));
  float* ogb     = (float*)carve((size_t)2*NLAYERS*64*sizeof(float));

  const int npart = (N_EDGES + EPB - 1)/EPB;   // 391
  prep_kernel<<<48, 256, 0, stream>>>(W1,b1,g1,be1,W2,b2,g2,be2,bng,bnb,Wt,bfb,ogb,btail,ftail);
  part1_kernel<<<npart, 256, 0, stream>>>(src, dst, btail, pairs);
  part2_kernel<<<NFINE, 256, 0, stream>>>(pairs, btail, ftail, pairs2);
  csr_kernel<<<NFINE, 256, 0, stream>>>(pairs2, ftail, offs, offe, srclist);
  xcvt_kernel<<<(N_NODES*CH/8 + 255)/256, 256, 0, stream>>>(x0, XB0);

  const int nlb = (N_NODES + 63)/64;   // 1563
  layer_kernel<<<nlb, 256, 0, stream>>>(XB0, offs, offe, srclist, eps, Wt, bfb, ogb, 0, OUT, (_Float16*)XB1, 1);
  layer_kernel<<<nlb, 256, 0, stream>>>(XB1, offs, offe, srclist, eps, Wt, bfb, ogb, 1, OUT, (_Float16*)XB0, 1);
  layer_kernel<<<nlb, 256, 0, stream>>>(XB0, offs, offe, srclist, eps, Wt, bfb, ogb, 2, OUT, (_Float16*)XB1, 0);
}